// Round 9
// baseline (560.167 us; speedup 1.0000x reference)
//
#include <hip/hip_runtime.h>
#include <cstdint>
#include <cstddef>

#define DIMC     512
#define D_INNER  1024
#define HEADDIM  128
#define NHEADS   8
#define D_STATE  128
#define CONV_DIM 1280
#define D_IN_PROJ 2312
#define NPAD     2432
#define BSZ      4
#define LSEQ     4096
#define BLTOT    (BSZ*LSEQ)   // 16384
#define QC       64           // SSD chunk length
#define NCH      (LSEQ/QC)    // 64 chunks

typedef short bf16x8 __attribute__((ext_vector_type(8)));
typedef float f32x4  __attribute__((ext_vector_type(4)));
typedef _Float16 f16x8 __attribute__((ext_vector_type(8)));
typedef _Float16 f16x4 __attribute__((ext_vector_type(4)));

__device__ inline ushort f2bf(float f) {
    uint32_t u = __float_as_uint(f);
    uint32_t r = (u + 0x7FFFu + ((u >> 16) & 1u)) >> 16;
    return (ushort)r;
}

// ---------------- K0a: transpose + convert x [b,d,l] fp32 -> xT [b,l,d] bf16 (for k1) ----------------
__global__ __launch_bounds__(256) void k0a_xT(const float* __restrict__ x, ushort* __restrict__ xT)
{
    __shared__ float t[32][33];
    const int bx = blockIdx.x;
    const int lt = bx & 127, dt = (bx >> 7) & 15, b = bx >> 11;
    const int r = threadIdx.x >> 5, c = threadIdx.x & 31;
    #pragma unroll
    for (int i = 0; i < 4; ++i) {
        int d = dt * 32 + r + i * 8;
        t[r + i * 8][c] = x[((size_t)(b * DIMC + d) << 12) + lt * 32 + c];
    }
    __syncthreads();
    #pragma unroll
    for (int i = 0; i < 4; ++i) {
        int l = lt * 32 + r + i * 8;
        xT[((size_t)(b * LSEQ + l)) * DIMC + dt * 32 + c] = f2bf(t[c][r + i * 8]);
    }
}

// ---------------- K0b: convert + pad in_proj_w -> bf16 [2432][512] ----------------
__global__ __launch_bounds__(256) void k0b_wb(const float* __restrict__ W, ushort* __restrict__ Wb)
{
    int i4 = (blockIdx.x * 256 + threadIdx.x) * 4;
    int e = i4 >> 9;
    ushort4 o;
    if (e < D_IN_PROJ) {
        float4 v = *(const float4*)(W + (size_t)e * DIMC + (i4 & 511));
        o.x = f2bf(v.x); o.y = f2bf(v.y); o.z = f2bf(v.z); o.w = f2bf(v.w);
    } else { o.x = o.y = o.z = o.w = 0; }
    *(ushort4*)(Wb + i4) = o;
}

// ---------------- K0c: convert out_proj_w -> bf16 [512][1024] ----------------
__global__ __launch_bounds__(256) void k0c_wout(const float* __restrict__ W, ushort* __restrict__ Wb)
{
    int i4 = (blockIdx.x * 256 + threadIdx.x) * 4;
    float4 v = *(const float4*)(W + i4);
    ushort4 o;
    o.x = f2bf(v.x); o.y = f2bf(v.y); o.z = f2bf(v.z); o.w = f2bf(v.w);
    *(ushort4*)(Wb + i4) = o;
}

// ---------------- K1: in_proj GEMM, bf16 MFMA, register-direct frags (no LDS, no barriers) ----------------
// A [16384][512] bf16 k-major, B [2432][512] bf16 k-major. Lane frag = 8 contiguous k.
__global__ __launch_bounds__(256) void k1_mfma(
    const ushort* __restrict__ A, const ushort* __restrict__ B,
    _Float16* __restrict__ zh, _Float16* __restrict__ xbcPre,
    float* __restrict__ dtp, float* __restrict__ ldA,
    const float* __restrict__ dt_bias, const float* __restrict__ A_log)
{
    const int tid = threadIdx.x;
    const int lane = tid & 63;
    const int wv = tid >> 6;
    const int wm = (wv & 1) * 64, wn = (wv >> 1) * 64;
    const int m0 = blockIdx.x * 128;
    const int n0 = blockIdx.y * 128;
    const int quad = lane >> 4, col = lane & 15;

    const ushort* Ap[4];
    const ushort* Bp[4];
    #pragma unroll
    for (int i = 0; i < 4; ++i) {
        Ap[i] = A + (size_t)(m0 + wm + i * 16 + col) * DIMC + quad * 8;
        Bp[i] = B + (size_t)(n0 + wn + i * 16 + col) * DIMC + quad * 8;
    }

    f32x4 acc[4][4];
    #pragma unroll
    for (int i = 0; i < 4; ++i)
        #pragma unroll
        for (int j = 0; j < 4; ++j) acc[i][j] = (f32x4){0.f, 0.f, 0.f, 0.f};

    bf16x8 af[2][4], bf_[2][4];
    #pragma unroll
    for (int i = 0; i < 4; ++i) {
        af[0][i]  = *(const bf16x8*)(Ap[i]);
        bf_[0][i] = *(const bf16x8*)(Bp[i]);
    }

    #pragma unroll
    for (int ks = 0; ks < 16; ++ks) {
        const int cur = ks & 1, nxt = cur ^ 1;
        if (ks < 15) {
            const int off = (ks + 1) * 32;
            #pragma unroll
            for (int i = 0; i < 4; ++i) {
                af[nxt][i]  = *(const bf16x8*)(Ap[i] + off);
                bf_[nxt][i] = *(const bf16x8*)(Bp[i] + off);
            }
        }
        #pragma unroll
        for (int mi = 0; mi < 4; ++mi)
            #pragma unroll
            for (int ni = 0; ni < 4; ++ni)
                acc[mi][ni] = __builtin_amdgcn_mfma_f32_16x16x32_bf16(af[cur][mi], bf_[cur][ni], acc[mi][ni], 0, 0, 0);
    }

    #pragma unroll
    for (int mi = 0; mi < 4; ++mi) {
        #pragma unroll
        for (int ni = 0; ni < 4; ++ni) {
            int e = n0 + wn + ni * 16 + col;
            #pragma unroll
            for (int reg = 0; reg < 4; ++reg) {
                int m = m0 + wm + mi * 16 + quad * 4 + reg;
                float v = acc[mi][ni][reg];
                if (e < D_INNER)                  zh[(size_t)m * D_INNER + e] = (_Float16)v;
                else if (e < D_INNER + CONV_DIM)  xbcPre[(size_t)m * CONV_DIM + (e - D_INNER)] = (_Float16)v;
                else if (e < D_IN_PROJ) {
                    int h = e - (D_INNER + CONV_DIM);
                    float v0 = v + dt_bias[h];
                    float sp = (v0 > 20.f) ? v0 : log1pf(expf(v0));
                    dtp[(size_t)m * NHEADS + h] = sp;
                    ldA[(size_t)m * NHEADS + h] = sp * (-expf(A_log[h]));
                }
            }
        }
    }
}

// ---------------- K3x: conv+silu channels 0..1023 -> xsT[b][p][t] f16 (transposed) ----------------
__global__ __launch_bounds__(256) void k3x(
    const _Float16* __restrict__ xbcPre, const float* __restrict__ cw,
    const float* __restrict__ cb, _Float16* __restrict__ xsT)
{
    __shared__ _Float16 tT[32][36];
    const int bx = blockIdx.x;
    const int ct = bx & 31, tt = (bx >> 5) & 127, b = bx >> 12;
    const int t0 = tt * 32, c0 = ct * 32;
    const int tid = threadIdx.x;
    const int tq = tid >> 3, cg = tid & 7;
    const int t = t0 + tq;
    const int c = c0 + cg * 4;
    const int m = b * LSEQ + t;

    float acc[4] = {cb[c], cb[c + 1], cb[c + 2], cb[c + 3]};
    #pragma unroll
    for (int j = 0; j < 4; ++j) {
        if (t - j >= 0) {
            f16x4 xv = *(const f16x4*)&xbcPre[(size_t)(m - j) * CONV_DIM + c];
            #pragma unroll
            for (int i = 0; i < 4; ++i)
                acc[i] = fmaf((float)xv[i], cw[(c + i) * 4 + (3 - j)], acc[i]);
        }
    }
    #pragma unroll
    for (int i = 0; i < 4; ++i) {
        float s = acc[i] / (1.f + expf(-acc[i]));
        tT[cg * 4 + i][tq] = (_Float16)s;
    }
    __syncthreads();
    const int r = tid >> 3, g = tid & 7;
    f16x4 o = *(const f16x4*)&tT[r][g * 4];
    *(f16x4*)&xsT[((size_t)b * D_INNER + c0 + r) * LSEQ + t0 + g * 4] = o;
}

// ---------------- K3bc: conv+silu channels 1024..1279 -> bcNat f16 + BT f16 ----------------
__global__ __launch_bounds__(256) void k3bc(
    const _Float16* __restrict__ xbcPre, const float* __restrict__ cw,
    const float* __restrict__ cb, _Float16* __restrict__ bcNat, _Float16* __restrict__ BT)
{
    __shared__ _Float16 tT[32][36];
    const int bx = blockIdx.x;
    const int ct = bx & 7, tt = (bx >> 3) & 127, b = bx >> 10;
    const int t0 = tt * 32, c0 = ct * 32;
    const int tid = threadIdx.x;
    const int tq = tid >> 3, cg = tid & 7;
    const int t = t0 + tq;
    const int ca = 1024 + c0 + cg * 4;
    const int m = b * LSEQ + t;

    float acc[4] = {cb[ca], cb[ca + 1], cb[ca + 2], cb[ca + 3]};
    #pragma unroll
    for (int j = 0; j < 4; ++j) {
        if (t - j >= 0) {
            f16x4 xv = *(const f16x4*)&xbcPre[(size_t)(m - j) * CONV_DIM + ca];
            #pragma unroll
            for (int i = 0; i < 4; ++i)
                acc[i] = fmaf((float)xv[i], cw[(ca + i) * 4 + (3 - j)], acc[i]);
        }
    }
    f16x4 nat;
    #pragma unroll
    for (int i = 0; i < 4; ++i) {
        float s = acc[i] / (1.f + expf(-acc[i]));
        nat[i] = (_Float16)s;
        tT[cg * 4 + i][tq] = nat[i];
    }
    *(f16x4*)&bcNat[(size_t)m * 256 + c0 + cg * 4] = nat;
    if (ct < 4) {
        __syncthreads();
        const int r = tid >> 3, g = tid & 7;
        f16x4 o = *(const f16x4*)&tT[r][g * 4];
        *(f16x4*)&BT[((size_t)b * D_STATE + c0 + r) * LSEQ + t0 + g * 4] = o;
    }
}

// ---------------- K4aA: per-chunk local state GEMM ----------------
__global__ __launch_bounds__(256) void k4aA(
    const _Float16* __restrict__ xsT, const _Float16* __restrict__ BT,
    const float* __restrict__ dtp, const float* __restrict__ ldA,
    _Float16* __restrict__ ST, float* __restrict__ Pbuf)
{
    __shared__ char smem[128 * 72 * 2 * 2 + 512];
    _Float16* sXTs = (_Float16*)smem;
    _Float16* sBT  = sXTs + 128 * 72;
    float* sW = (float*)(sBT + 128 * 72);
    _Float16* sOut = sXTs;

    const int tid = threadIdx.x;
    const int lane = tid & 63;
    const int wv = tid >> 6;
    const int quad = lane >> 4, l15 = lane & 15;
    const int c = blockIdx.x & 63;
    const int h = (blockIdx.x >> 6) & 7;
    const int b = blockIdx.x >> 9;
    const int bh = b * NHEADS + h;
    const size_t mbase = (size_t)b * LSEQ + c * QC;

    if (tid < 64) {
        size_t gi = (mbase + tid) * NHEADS + h;
        float ld = ldA[gi];
        float dtv = dtp[gi];
        float cum = ld;
        #pragma unroll
        for (int off = 1; off < 64; off <<= 1) {
            float v = __shfl_up(cum, off);
            if (tid >= off) cum += v;
        }
        float cum63 = __shfl(cum, 63);
        sW[tid] = expf(cum63 - cum) * dtv;
        if (tid == 63) Pbuf[bh * NCH + c] = expf(cum63);
    }
    __syncthreads();

    #pragma unroll
    for (int k = 0; k < 4; ++k) {
        int idx = k * 256 + tid;
        int row = idx >> 3, g = idx & 7;
        int t0 = g * 8;
        f16x8 hv = *(const f16x8*)&xsT[((size_t)b * D_INNER + h * HEADDIM + row) * LSEQ + c * QC + t0];
        f16x8 sv;
        #pragma unroll
        for (int j = 0; j < 8; ++j) sv[j] = (_Float16)((float)hv[j] * sW[t0 + j]);
        *(f16x8*)&sXTs[row * 72 + t0] = sv;
        int4 bv = *(const int4*)&BT[((size_t)b * D_STATE + row) * LSEQ + c * QC + t0];
        *(int4*)&sBT[row * 72 + t0] = bv;
    }
    __syncthreads();

    f32x4 acc[2][8];
    #pragma unroll
    for (int i = 0; i < 2; ++i)
        #pragma unroll
        for (int j = 0; j < 8; ++j) acc[i][j] = (f32x4){0.f, 0.f, 0.f, 0.f};

    #pragma unroll
    for (int kk = 0; kk < 2; ++kk) {
        f16x8 af[2];
        #pragma unroll
        for (int mi = 0; mi < 2; ++mi)
            af[mi] = *(const f16x8*)&sXTs[(wv * 32 + mi * 16 + l15) * 72 + kk * 32 + quad * 8];
        #pragma unroll
        for (int ni = 0; ni < 8; ++ni) {
            f16x8 bf_ = *(const f16x8*)&sBT[(ni * 16 + l15) * 72 + kk * 32 + quad * 8];
            #pragma unroll
            for (int mi = 0; mi < 2; ++mi)
                acc[mi][ni] = __builtin_amdgcn_mfma_f32_16x16x32_f16(af[mi], bf_, acc[mi][ni], 0, 0, 0);
        }
    }
    __syncthreads();
    #pragma unroll
    for (int mi = 0; mi < 2; ++mi)
        #pragma unroll
        for (int ni = 0; ni < 8; ++ni)
            #pragma unroll
            for (int reg = 0; reg < 4; ++reg) {
                int p = wv * 32 + mi * 16 + quad * 4 + reg;
                int n = ni * 16 + l15;
                sOut[p * 136 + n] = (_Float16)acc[mi][ni][reg];
            }
    __syncthreads();
    _Float16* stg = ST + ((size_t)bh * NCH + c) * (HEADDIM * D_STATE);
    #pragma unroll
    for (int k = 0; k < 8; ++k) {
        int idx = k * 256 + tid;
        int row = idx >> 4, g = idx & 15;
        int4 v = *(const int4*)&sOut[row * 136 + g * 8];
        *(int4*)&stg[row * 128 + g * 8] = v;
    }
}

// ---------------- K4bB: 64-chunk state prefix (in place) ----------------
__global__ __launch_bounds__(256) void k4bB(_Float16* __restrict__ ST, const float* __restrict__ Pbuf)
{
    __shared__ float sp_[NCH];
    const int bh = blockIdx.x >> 4;
    const int seg = blockIdx.x & 15;
    const int tid = threadIdx.x;
    if (tid < NCH) sp_[tid] = Pbuf[bh * NCH + tid];
    __syncthreads();
    const int e = seg * 1024 + tid * 4;
    float r0 = 0.f, r1 = 0.f, r2 = 0.f, r3 = 0.f;
    for (int c = 0; c < NCH; ++c) {
        _Float16* ptr = ST + ((size_t)bh * NCH + c) * (HEADDIM * D_STATE) + e;
        f16x4 v = *(const f16x4*)ptr;
        float f0 = (float)v[0], f1 = (float)v[1], f2 = (float)v[2], f3 = (float)v[3];
        f16x4 o; o[0] = (_Float16)r0; o[1] = (_Float16)r1; o[2] = (_Float16)r2; o[3] = (_Float16)r3;
        *(f16x4*)ptr = o;
        float P = sp_[c];
        r0 = fmaf(r0, P, f0); r1 = fmaf(r1, P, f1);
        r2 = fmaf(r2, P, f2); r3 = fmaf(r3, P, f3);
    }
}

// ---------------- K4cC: per-chunk y via SSD GEMMs ----------------
__global__ __launch_bounds__(256) void k4cC(
    const _Float16* __restrict__ bcNat, const _Float16* __restrict__ xsT,
    const _Float16* __restrict__ sinit, const float* __restrict__ dtp,
    const float* __restrict__ ldA, const float* __restrict__ Dp,
    _Float16* __restrict__ yB)
{
    __shared__ char smem[(64*136 + 64*136 + 128*72 + 4*16*72) * 2 + 640];
    _Float16* sC  = (_Float16*)smem;
    _Float16* sB  = sC + 64 * 136;
    _Float16* sXT = sB + 64 * 136;
    _Float16* sM  = sXT + 128 * 72;
    float* scum = (float*)(sM + 4 * 16 * 72);
    float* sdt  = scum + 64;
    _Float16* sIni = sB;
    _Float16* sY  = sC;

    const int tid = threadIdx.x;
    const int lane = tid & 63;
    const int wv = tid >> 6;
    const int quad = lane >> 4, l15 = lane & 15;
    const int c = blockIdx.x & 63;
    const int h = (blockIdx.x >> 6) & 7;
    const int b = blockIdx.x >> 9;
    const int bh = b * NHEADS + h;
    const size_t mbase = (size_t)b * LSEQ + c * QC;
    const float Dh = Dp[h];

    if (tid < 64) {
        size_t gi = (mbase + tid) * NHEADS + h;
        float ld = ldA[gi];
        float dtv = dtp[gi];
        float cum = ld;
        #pragma unroll
        for (int off = 1; off < 64; off <<= 1) {
            float v = __shfl_up(cum, off);
            if (tid >= off) cum += v;
        }
        scum[tid] = cum;
        sdt[tid] = dtv;
    }
    #pragma unroll
    for (int k = 0; k < 4; ++k) {
        int idx = k * 256 + tid;
        int t = idx >> 4, g = idx & 15;
        const _Float16* row = bcNat + (mbase + t) * 256;
        *(int4*)&sB[t * 136 + g * 8] = *(const int4*)&row[g * 8];
        *(int4*)&sC[t * 136 + g * 8] = *(const int4*)&row[128 + g * 8];
        int idx2 = k * 256 + tid;
        int p = idx2 >> 3, g2 = idx2 & 7;
        *(int4*)&sXT[p * 72 + g2 * 8] =
            *(const int4*)&xsT[((size_t)b * D_INNER + h * HEADDIM + p) * LSEQ + c * QC + g2 * 8];
    }
    __syncthreads();

    // G = C @ B^T
    f32x4 g[4];
    #pragma unroll
    for (int j = 0; j < 4; ++j) g[j] = (f32x4){0.f, 0.f, 0.f, 0.f};
    #pragma unroll
    for (int kk = 0; kk < 4; ++kk) {
        f16x8 af = *(const f16x8*)&sC[(wv * 16 + l15) * 136 + kk * 32 + quad * 8];
        #pragma unroll
        for (int tt = 0; tt < 4; ++tt) {
            f16x8 bf_ = *(const f16x8*)&sB[(tt * 16 + l15) * 136 + kk * 32 + quad * 8];
            g[tt] = __builtin_amdgcn_mfma_f32_16x16x32_f16(af, bf_, g[tt], 0, 0, 0);
        }
    }
    _Float16* sMw = sM + wv * 16 * 72;
    #pragma unroll
    for (int tt = 0; tt < 4; ++tt) {
        int tau = tt * 16 + l15;
        #pragma unroll
        for (int reg = 0; reg < 4; ++reg) {
            int trow = quad * 4 + reg;
            int tglob = wv * 16 + trow;
            float mval;
            if (tau > tglob) mval = 0.f;
            else if (tau == tglob) mval = g[tt][reg] * sdt[tau] + Dh;
            else mval = g[tt][reg] * expf(scum[tglob] - scum[tau]) * sdt[tau];
            sMw[trow * 72 + tau] = (_Float16)mval;
        }
    }
    asm volatile("s_waitcnt lgkmcnt(0)" ::: "memory");

    // Y1 = M @ X^T
    f32x4 y[8];
    #pragma unroll
    for (int j = 0; j < 8; ++j) y[j] = (f32x4){0.f, 0.f, 0.f, 0.f};
    #pragma unroll
    for (int kk = 0; kk < 2; ++kk) {
        f16x8 af = *(const f16x8*)&sMw[l15 * 72 + kk * 32 + quad * 8];
        #pragma unroll
        for (int pi = 0; pi < 8; ++pi) {
            f16x8 bf_ = *(const f16x8*)&sXT[(pi * 16 + l15) * 72 + kk * 32 + quad * 8];
            y[pi] = __builtin_amdgcn_mfma_f32_16x16x32_f16(af, bf_, y[pi], 0, 0, 0);
        }
    }
    __syncthreads();
    {
        const _Float16* sg = sinit + ((size_t)bh * NCH + c) * (HEADDIM * D_STATE);
        #pragma unroll
        for (int k = 0; k < 8; ++k) {
            int idx = k * 256 + tid;
            int p = idx >> 4, gg = idx & 15;
            *(int4*)&sIni[p * 136 + gg * 8] = *(const int4*)&sg[p * 128 + gg * 8];
        }
    }
    __syncthreads();
    // Y2 += (e^cum * C) @ s_init^T
    {
        float ea = expf(scum[wv * 16 + l15]);
        #pragma unroll
        for (int kk = 0; kk < 4; ++kk) {
            f16x8 cf = *(const f16x8*)&sC[(wv * 16 + l15) * 136 + kk * 32 + quad * 8];
            f16x8 af;
            #pragma unroll
            for (int j = 0; j < 8; ++j) af[j] = (_Float16)((float)cf[j] * ea);
            #pragma unroll
            for (int pi = 0; pi < 8; ++pi) {
                f16x8 bf_ = *(const f16x8*)&sIni[(pi * 16 + l15) * 136 + kk * 32 + quad * 8];
                y[pi] = __builtin_amdgcn_mfma_f32_16x16x32_f16(af, bf_, y[pi], 0, 0, 0);
            }
        }
    }
    __syncthreads();
    #pragma unroll
    for (int pi = 0; pi < 8; ++pi)
        #pragma unroll
        for (int reg = 0; reg < 4; ++reg) {
            int trow = wv * 16 + quad * 4 + reg;
            int p = pi * 16 + l15;
            sY[trow * 136 + p] = (_Float16)y[pi][reg];
        }
    __syncthreads();
    #pragma unroll
    for (int k = 0; k < 4; ++k) {
        int idx = k * 256 + tid;
        int t = idx >> 4, gg = idx & 15;
        int4 v = *(const int4*)&sY[t * 136 + gg * 8];
        *(int4*)&yB[(mbase + t) * D_INNER + h * HEADDIM + gg * 8] = v;
    }
}

// ---------------- K5: y *= silu(z); RMSNorm * norm_w -> bf16 (in place over yB) ----------------
__global__ __launch_bounds__(256) void k5_norm(
    const _Float16* __restrict__ yB, const _Float16* __restrict__ zh,
    const float* __restrict__ nw, ushort* __restrict__ ybB)
{
    const int m = blockIdx.x;
    const int tid = threadIdx.x;
    const size_t off = (size_t)m * D_INNER + tid * 4;
    f16x4 yv = *(const f16x4*)&yB[off];
    f16x4 zv = *(const f16x4*)&zh[off];
    float4 gv;
    {
        float z0 = (float)zv[0], z1 = (float)zv[1], z2 = (float)zv[2], z3 = (float)zv[3];
        gv.x = (float)yv[0] * (z0 / (1.f + expf(-z0)));
        gv.y = (float)yv[1] * (z1 / (1.f + expf(-z1)));
        gv.z = (float)yv[2] * (z2 / (1.f + expf(-z2)));
        gv.w = (float)yv[3] * (z3 / (1.f + expf(-z3)));
    }
    float ss = gv.x*gv.x + gv.y*gv.y + gv.z*gv.z + gv.w*gv.w;
    #pragma unroll
    for (int mask = 1; mask <= 32; mask <<= 1) ss += __shfl_xor(ss, mask);
    __shared__ float red[4];
    if ((tid & 63) == 0) red[tid >> 6] = ss;
    __syncthreads();
    float tot = red[0] + red[1] + red[2] + red[3];
    float scale = rsqrtf(tot * (1.f / 1024.f) + 1e-5f);
    float4 w4 = *(const float4*)(nw + tid * 4);
    ushort4 ob;
    ob.x = f2bf(gv.x * scale * w4.x);
    ob.y = f2bf(gv.y * scale * w4.y);
    ob.z = f2bf(gv.z * scale * w4.z);
    ob.w = f2bf(gv.w * scale * w4.w);
    *(ushort4*)(ybB + off) = ob;
}

// ---------------- K6: out_proj GEMM bf16 MFMA + residual, register-direct frags ----------------
__global__ __launch_bounds__(256) void k6_mfma(
    const ushort* __restrict__ A, const ushort* __restrict__ B,
    const float* __restrict__ x, float* __restrict__ out)
{
    const int tid = threadIdx.x;
    const int lane = tid & 63;
    const int wv = tid >> 6;
    const int wm = (wv & 1) * 64, wn = (wv >> 1) * 64;
    const int m0 = blockIdx.x * 128;
    const int n0 = blockIdx.y * 128;
    const int quad = lane >> 4, col = lane & 15;

    const ushort* Ap[4];
    const ushort* Bp[4];
    #pragma unroll
    for (int i = 0; i < 4; ++i) {
        Ap[i] = A + (size_t)(m0 + wm + i * 16 + col) * D_INNER + quad * 8;
        Bp[i] = B + (size_t)(n0 + wn + i * 16 + col) * D_INNER + quad * 8;
    }

    f32x4 acc[4][4];
    #pragma unroll
    for (int i = 0; i < 4; ++i)
        #pragma unroll
        for (int j = 0; j < 4; ++j) acc[i][j] = (f32x4){0.f, 0.f, 0.f, 0.f};

    bf16x8 af[2][4], bf_[2][4];
    #pragma unroll
    for (int i = 0; i < 4; ++i) {
        af[0][i]  = *(const bf16x8*)(Ap[i]);
        bf_[0][i] = *(const bf16x8*)(Bp[i]);
    }

    #pragma unroll
    for (int ks = 0; ks < 32; ++ks) {
        const int cur = ks & 1, nxt = cur ^ 1;
        if (ks < 31) {
            const int off = (ks + 1) * 32;
            #pragma unroll
            for (int i = 0; i < 4; ++i) {
                af[nxt][i]  = *(const bf16x8*)(Ap[i] + off);
                bf_[nxt][i] = *(const bf16x8*)(Bp[i] + off);
            }
        }
        #pragma unroll
        for (int mi = 0; mi < 4; ++mi)
            #pragma unroll
            for (int ni = 0; ni < 4; ++ni)
                acc[mi][ni] = __builtin_amdgcn_mfma_f32_16x16x32_bf16(af[cur][mi], bf_[cur][ni], acc[mi][ni], 0, 0, 0);
    }

    #pragma unroll
    for (int mi = 0; mi < 4; ++mi) {
        #pragma unroll
        for (int ni = 0; ni < 4; ++ni) {
            int mm = n0 + wn + ni * 16 + col;
            int b = mm >> 12, l = mm & 4095;
            #pragma unroll
            for (int reg = 0; reg < 4; ++reg) {
                int d = m0 + wm + mi * 16 + quad * 4 + reg;
                size_t o = ((size_t)(b * DIMC + d) << 12) + l;
                out[o] = acc[mi][ni][reg] + x[o];
            }
        }
    }
}

extern "C" void kernel_launch(void* const* d_in, const int* in_sizes, int n_in,
                              void* d_out, int out_size, void* d_ws, size_t ws_size,
                              hipStream_t stream) {
    const float* x          = (const float*)d_in[0];
    const float* in_proj_w  = (const float*)d_in[1];
    const float* conv_w     = (const float*)d_in[2];
    const float* conv_b     = (const float*)d_in[3];
    const float* dt_bias    = (const float*)d_in[4];
    const float* A_log      = (const float*)d_in[5];
    const float* D_param    = (const float*)d_in[6];
    const float* norm_w     = (const float*)d_in[7];
    const float* out_proj_w = (const float*)d_in[8];
    float* out = (float*)d_out;

    float* ws = (float*)d_ws;
    float* zbuf = ws;                                      // region A: 16,777,216 f32
    _Float16* zh = (_Float16*)zbuf;                        // z stored f16
    float* regB = zbuf + (size_t)16777216;
    _Float16* xbcPre = (_Float16*)regB;                    // 16384x1280 f16
    _Float16* yB     = (_Float16*)regB;                    // 16384x1024 f16 (after k3)
    float* dtb  = regB + (size_t)10485760;                 // (unused slot, kept for layout)
    float* dtp  = dtb + 131072;
    float* ldA  = dtp + 131072;
    float* Pbuf = ldA + 131072;                            // 2048
    float* regD = Pbuf + 2048;
    ushort* xT_k1 = (ushort*)regD;                         // 16384x512 bf16
    ushort* Wb    = xT_k1 + (size_t)BLTOT * DIMC;          // 2432x512 bf16
    _Float16* ST  = (_Float16*)regD;                       // 32x64x128x128 f16 (after k1)
    float* regE = regD + (size_t)16777216;
    _Float16* xsT   = (_Float16*)regE;                     // 4x1024x4096 f16
    _Float16* BT    = xsT + (size_t)BSZ * D_INNER * LSEQ;  // 4x128x4096 f16
    _Float16* bcNat = BT + (size_t)BSZ * D_STATE * LSEQ;   // 16384x256 f16
    ushort* woutB = (ushort*)zbuf;                         // after k5

    k0a_xT<<<dim3(8192), dim3(256), 0, stream>>>(x, xT_k1);
    k0b_wb<<<dim3(NPAD * DIMC / 1024), dim3(256), 0, stream>>>(in_proj_w, Wb);
    k1_mfma<<<dim3(128, 19), dim3(256), 0, stream>>>(xT_k1, Wb, zh, xbcPre, dtp, ldA, dt_bias, A_log);
    k3x<<<dim3(16384), dim3(256), 0, stream>>>(xbcPre, conv_w, conv_b, xsT);
    k3bc<<<dim3(4096), dim3(256), 0, stream>>>(xbcPre, conv_w, conv_b, bcNat, BT);
    k4aA<<<dim3(2048), dim3(256), 0, stream>>>(xsT, BT, dtp, ldA, ST, Pbuf);
    k4bB<<<dim3(512), dim3(256), 0, stream>>>(ST, Pbuf);
    k4cC<<<dim3(2048), dim3(256), 0, stream>>>(bcNat, xsT, ST, dtp, ldA, D_param, yB);
    k5_norm<<<dim3(BLTOT), dim3(256), 0, stream>>>(yB, zh, norm_w, (ushort*)yB);
    k0c_wout<<<dim3(512), dim3(256), 0, stream>>>(out_proj_w, woutB);
    k6_mfma<<<dim3(4, 128), dim3(256), 0, stream>>>(woutB, (ushort*)yB, x, out);
}

// Round 10
// 412.421 us; speedup vs baseline: 1.3582x; 1.3582x over previous
//
#include <hip/hip_runtime.h>
#include <cstdint>
#include <cstddef>

#define DIMC     512
#define D_INNER  1024
#define HEADDIM  128
#define NHEADS   8
#define D_STATE  128
#define CONV_DIM 1280
#define D_IN_PROJ 2312
#define NPAD     2432
#define BSZ      4
#define LSEQ     4096
#define BLTOT    (BSZ*LSEQ)   // 16384
#define QC       64           // SSD chunk length
#define NCH      (LSEQ/QC)    // 64 chunks

typedef short bf16x8 __attribute__((ext_vector_type(8)));
typedef float f32x4  __attribute__((ext_vector_type(4)));
typedef _Float16 f16x8 __attribute__((ext_vector_type(8)));
typedef _Float16 f16x4 __attribute__((ext_vector_type(4)));

__device__ inline ushort f2bf(float f) {
    uint32_t u = __float_as_uint(f);
    uint32_t r = (u + 0x7FFFu + ((u >> 16) & 1u)) >> 16;
    return (ushort)r;
}

// async global->LDS, 16B per lane; lds base must be wave-uniform
__device__ __forceinline__ void gload_lds16(const void* g, void* l) {
    __builtin_amdgcn_global_load_lds(
        (const __attribute__((address_space(1))) void*)g,
        (__attribute__((address_space(3))) void*)l,
        16, 0, 0);
}

// ---------------- K0: fused prep. blocks [0,8192): x transpose->bf16; [8192,9408): Wb; [9408,9920): wout ----------------
__global__ __launch_bounds__(256) void k0_prep(
    const float* __restrict__ x, ushort* __restrict__ xT,
    const float* __restrict__ Win, ushort* __restrict__ Wb,
    const float* __restrict__ Wout, ushort* __restrict__ WoutB)
{
    const int bx = blockIdx.x;
    if (bx < 8192) {
        __shared__ float t[32][33];
        const int lt = bx & 127, dt = (bx >> 7) & 15, b = bx >> 11;
        const int r = threadIdx.x >> 5, c = threadIdx.x & 31;
        #pragma unroll
        for (int i = 0; i < 4; ++i) {
            int d = dt * 32 + r + i * 8;
            t[r + i * 8][c] = x[((size_t)(b * DIMC + d) << 12) + lt * 32 + c];
        }
        __syncthreads();
        #pragma unroll
        for (int i = 0; i < 4; ++i) {
            int l = lt * 32 + r + i * 8;
            xT[((size_t)(b * LSEQ + l)) * DIMC + dt * 32 + c] = f2bf(t[c][r + i * 8]);
        }
    } else if (bx < 9408) {
        int i4 = ((bx - 8192) * 256 + threadIdx.x) * 4;   // NPAD*512
        int e = i4 >> 9;
        ushort4 o;
        if (e < D_IN_PROJ) {
            float4 v = *(const float4*)(Win + (size_t)e * DIMC + (i4 & 511));
            o.x = f2bf(v.x); o.y = f2bf(v.y); o.z = f2bf(v.z); o.w = f2bf(v.w);
        } else { o.x = o.y = o.z = o.w = 0; }
        *(ushort4*)(Wb + i4) = o;
    } else {
        int i4 = ((bx - 9408) * 256 + threadIdx.x) * 4;   // 512*1024
        float4 v = *(const float4*)(Wout + i4);
        ushort4 o;
        o.x = f2bf(v.x); o.y = f2bf(v.y); o.z = f2bf(v.z); o.w = f2bf(v.w);
        *(ushort4*)(WoutB + i4) = o;
    }
}

// ---------------- K1: in_proj GEMM, bf16 MFMA, BK=32 global_load_lds, fused dt epilogue ----------------
__global__ __launch_bounds__(256) void k1_mfma(
    const ushort* __restrict__ A, const ushort* __restrict__ B,
    _Float16* __restrict__ zh, _Float16* __restrict__ xbcPre,
    float* __restrict__ dtp, float* __restrict__ ldA,
    const float* __restrict__ dt_bias, const float* __restrict__ A_log)
{
    __shared__ ushort sA[128 * 32];
    __shared__ ushort sB[128 * 32];
    const int tid = threadIdx.x;
    const int lane = tid & 63;
    const int wv = tid >> 6;
    const int wm = (wv & 1) * 64, wn = (wv >> 1) * 64;
    const int m0 = blockIdx.x * 128;
    const int n0 = blockIdx.y * 128;

    f32x4 acc[4][4];
    #pragma unroll
    for (int i = 0; i < 4; ++i)
        #pragma unroll
        for (int j = 0; j < 4; ++j) acc[i][j] = (f32x4){0.f, 0.f, 0.f, 0.f};

    // slot s holds row r=s>>2, k8=(s&3)^((r>>1)&3); slots: tid, tid+256
    const int r0 = tid >> 2, c0 = tid & 3, k80 = c0 ^ ((r0 >> 1) & 3);
    const int s1_ = tid + 256;
    const int r1 = s1_ >> 2, c1 = s1_ & 3, k81 = c1 ^ ((r1 >> 1) & 3);
    const int quad = lane >> 4, col = lane & 15;
    ushort* lA0 = sA + (size_t)(wv * 64) * 8;
    ushort* lA1 = sA + (size_t)(256 + wv * 64) * 8;
    ushort* lB0 = sB + (size_t)(wv * 64) * 8;
    ushort* lB1 = sB + (size_t)(256 + wv * 64) * 8;

    for (int kb = 0; kb < DIMC; kb += 32) {
        gload_lds16(A + (size_t)(m0 + r0) * DIMC + kb + k80 * 8, lA0);
        gload_lds16(A + (size_t)(m0 + r1) * DIMC + kb + k81 * 8, lA1);
        gload_lds16(B + (size_t)(n0 + r0) * DIMC + kb + k80 * 8, lB0);
        gload_lds16(B + (size_t)(n0 + r1) * DIMC + kb + k81 * 8, lB1);
        __syncthreads();
        bf16x8 af[4], bf_[4];
        #pragma unroll
        for (int mi = 0; mi < 4; ++mi) {
            int m = wm + mi * 16 + col;
            int ch = quad ^ ((m >> 1) & 3);
            af[mi] = *(const bf16x8*)&sA[m * 32 + ch * 8];
        }
        #pragma unroll
        for (int ni = 0; ni < 4; ++ni) {
            int n = wn + ni * 16 + col;
            int ch = quad ^ ((n >> 1) & 3);
            bf_[ni] = *(const bf16x8*)&sB[n * 32 + ch * 8];
        }
        #pragma unroll
        for (int mi = 0; mi < 4; ++mi)
            #pragma unroll
            for (int ni = 0; ni < 4; ++ni)
                acc[mi][ni] = __builtin_amdgcn_mfma_f32_16x16x32_bf16(af[mi], bf_[ni], acc[mi][ni], 0, 0, 0);
        __syncthreads();
    }

    #pragma unroll
    for (int mi = 0; mi < 4; ++mi) {
        #pragma unroll
        for (int ni = 0; ni < 4; ++ni) {
            int e = n0 + wn + ni * 16 + col;
            #pragma unroll
            for (int reg = 0; reg < 4; ++reg) {
                int m = m0 + wm + mi * 16 + quad * 4 + reg;
                float v = acc[mi][ni][reg];
                if (e < D_INNER)                  zh[(size_t)m * D_INNER + e] = (_Float16)v;
                else if (e < D_INNER + CONV_DIM)  xbcPre[(size_t)m * CONV_DIM + (e - D_INNER)] = (_Float16)v;
                else if (e < D_IN_PROJ) {
                    int h = e - (D_INNER + CONV_DIM);
                    float v0 = v + dt_bias[h];
                    float sp = (v0 > 20.f) ? v0 : log1pf(expf(v0));
                    dtp[(size_t)m * NHEADS + h] = sp;
                    ldA[(size_t)m * NHEADS + h] = sp * (-expf(A_log[h]));
                }
            }
        }
    }
}

// ---------------- K3: fused conv+silu. blocks [0,16384): x-channels -> xsT; [16384,20480): B/C channels ----------------
__global__ __launch_bounds__(256) void k3_conv(
    const _Float16* __restrict__ xbcPre, const float* __restrict__ cw,
    const float* __restrict__ cb, _Float16* __restrict__ xsT,
    _Float16* __restrict__ bcNat, _Float16* __restrict__ BT)
{
    __shared__ _Float16 tT[32][36];
    const int tid = threadIdx.x;
    const int tq = tid >> 3, cg = tid & 7;
    if (blockIdx.x < 16384) {
        const int bx = blockIdx.x;
        const int ct = bx & 31, tt = (bx >> 5) & 127, b = bx >> 12;
        const int t0 = tt * 32, c0 = ct * 32;
        const int t = t0 + tq;
        const int c = c0 + cg * 4;
        const int m = b * LSEQ + t;

        float acc[4] = {cb[c], cb[c + 1], cb[c + 2], cb[c + 3]};
        #pragma unroll
        for (int j = 0; j < 4; ++j) {
            if (t - j >= 0) {
                f16x4 xv = *(const f16x4*)&xbcPre[(size_t)(m - j) * CONV_DIM + c];
                #pragma unroll
                for (int i = 0; i < 4; ++i)
                    acc[i] = fmaf((float)xv[i], cw[(c + i) * 4 + (3 - j)], acc[i]);
            }
        }
        #pragma unroll
        for (int i = 0; i < 4; ++i) {
            float s = acc[i] / (1.f + expf(-acc[i]));
            tT[cg * 4 + i][tq] = (_Float16)s;
        }
        __syncthreads();
        const int r = tid >> 3, g = tid & 7;
        f16x4 o = *(const f16x4*)&tT[r][g * 4];
        *(f16x4*)&xsT[((size_t)b * D_INNER + c0 + r) * LSEQ + t0 + g * 4] = o;
    } else {
        const int bx = blockIdx.x - 16384;
        const int ct = bx & 7, tt = (bx >> 3) & 127, b = bx >> 10;
        const int t0 = tt * 32, c0 = ct * 32;
        const int t = t0 + tq;
        const int ca = 1024 + c0 + cg * 4;
        const int m = b * LSEQ + t;

        float acc[4] = {cb[ca], cb[ca + 1], cb[ca + 2], cb[ca + 3]};
        #pragma unroll
        for (int j = 0; j < 4; ++j) {
            if (t - j >= 0) {
                f16x4 xv = *(const f16x4*)&xbcPre[(size_t)(m - j) * CONV_DIM + ca];
                #pragma unroll
                for (int i = 0; i < 4; ++i)
                    acc[i] = fmaf((float)xv[i], cw[(ca + i) * 4 + (3 - j)], acc[i]);
            }
        }
        f16x4 nat;
        #pragma unroll
        for (int i = 0; i < 4; ++i) {
            float s = acc[i] / (1.f + expf(-acc[i]));
            nat[i] = (_Float16)s;
            tT[cg * 4 + i][tq] = nat[i];
        }
        *(f16x4*)&bcNat[(size_t)m * 256 + c0 + cg * 4] = nat;
        if (ct < 4) {
            __syncthreads();
            const int r = tid >> 3, g = tid & 7;
            f16x4 o = *(const f16x4*)&tT[r][g * 4];
            *(f16x4*)&BT[((size_t)b * D_STATE + c0 + r) * LSEQ + t0 + g * 4] = o;
        }
    }
}

// ---------------- K4aA: per-chunk local state GEMM ----------------
__global__ __launch_bounds__(256) void k4aA(
    const _Float16* __restrict__ xsT, const _Float16* __restrict__ BT,
    const float* __restrict__ dtp, const float* __restrict__ ldA,
    _Float16* __restrict__ ST, float* __restrict__ Pbuf)
{
    __shared__ char smem[128 * 72 * 2 * 2 + 512];
    _Float16* sXTs = (_Float16*)smem;
    _Float16* sBT  = sXTs + 128 * 72;
    float* sW = (float*)(sBT + 128 * 72);
    _Float16* sOut = sXTs;

    const int tid = threadIdx.x;
    const int lane = tid & 63;
    const int wv = tid >> 6;
    const int quad = lane >> 4, l15 = lane & 15;
    const int c = blockIdx.x & 63;
    const int h = (blockIdx.x >> 6) & 7;
    const int b = blockIdx.x >> 9;
    const int bh = b * NHEADS + h;
    const size_t mbase = (size_t)b * LSEQ + c * QC;

    if (tid < 64) {
        size_t gi = (mbase + tid) * NHEADS + h;
        float ld = ldA[gi];
        float dtv = dtp[gi];
        float cum = ld;
        #pragma unroll
        for (int off = 1; off < 64; off <<= 1) {
            float v = __shfl_up(cum, off);
            if (tid >= off) cum += v;
        }
        float cum63 = __shfl(cum, 63);
        sW[tid] = expf(cum63 - cum) * dtv;
        if (tid == 63) Pbuf[bh * NCH + c] = expf(cum63);
    }
    __syncthreads();

    #pragma unroll
    for (int k = 0; k < 4; ++k) {
        int idx = k * 256 + tid;
        int row = idx >> 3, g = idx & 7;
        int t0 = g * 8;
        f16x8 hv = *(const f16x8*)&xsT[((size_t)b * D_INNER + h * HEADDIM + row) * LSEQ + c * QC + t0];
        f16x8 sv;
        #pragma unroll
        for (int j = 0; j < 8; ++j) sv[j] = (_Float16)((float)hv[j] * sW[t0 + j]);
        *(f16x8*)&sXTs[row * 72 + t0] = sv;
        int4 bv = *(const int4*)&BT[((size_t)b * D_STATE + row) * LSEQ + c * QC + t0];
        *(int4*)&sBT[row * 72 + t0] = bv;
    }
    __syncthreads();

    f32x4 acc[2][8];
    #pragma unroll
    for (int i = 0; i < 2; ++i)
        #pragma unroll
        for (int j = 0; j < 8; ++j) acc[i][j] = (f32x4){0.f, 0.f, 0.f, 0.f};

    #pragma unroll
    for (int kk = 0; kk < 2; ++kk) {
        f16x8 af[2];
        #pragma unroll
        for (int mi = 0; mi < 2; ++mi)
            af[mi] = *(const f16x8*)&sXTs[(wv * 32 + mi * 16 + l15) * 72 + kk * 32 + quad * 8];
        #pragma unroll
        for (int ni = 0; ni < 8; ++ni) {
            f16x8 bf_ = *(const f16x8*)&sBT[(ni * 16 + l15) * 72 + kk * 32 + quad * 8];
            #pragma unroll
            for (int mi = 0; mi < 2; ++mi)
                acc[mi][ni] = __builtin_amdgcn_mfma_f32_16x16x32_f16(af[mi], bf_, acc[mi][ni], 0, 0, 0);
        }
    }
    __syncthreads();
    #pragma unroll
    for (int mi = 0; mi < 2; ++mi)
        #pragma unroll
        for (int ni = 0; ni < 8; ++ni)
            #pragma unroll
            for (int reg = 0; reg < 4; ++reg) {
                int p = wv * 32 + mi * 16 + quad * 4 + reg;
                int n = ni * 16 + l15;
                sOut[p * 136 + n] = (_Float16)acc[mi][ni][reg];
            }
    __syncthreads();
    _Float16* stg = ST + ((size_t)bh * NCH + c) * (HEADDIM * D_STATE);
    #pragma unroll
    for (int k = 0; k < 8; ++k) {
        int idx = k * 256 + tid;
        int row = idx >> 4, g = idx & 15;
        int4 v = *(const int4*)&sOut[row * 136 + g * 8];
        *(int4*)&stg[row * 128 + g * 8] = v;
    }
}

// ---------------- K4bB: 64-chunk state prefix (in place) ----------------
__global__ __launch_bounds__(256) void k4bB(_Float16* __restrict__ ST, const float* __restrict__ Pbuf)
{
    __shared__ float sp_[NCH];
    const int bh = blockIdx.x >> 4;
    const int seg = blockIdx.x & 15;
    const int tid = threadIdx.x;
    if (tid < NCH) sp_[tid] = Pbuf[bh * NCH + tid];
    __syncthreads();
    const int e = seg * 1024 + tid * 4;
    float r0 = 0.f, r1 = 0.f, r2 = 0.f, r3 = 0.f;
    for (int c = 0; c < NCH; ++c) {
        _Float16* ptr = ST + ((size_t)bh * NCH + c) * (HEADDIM * D_STATE) + e;
        f16x4 v = *(const f16x4*)ptr;
        float f0 = (float)v[0], f1 = (float)v[1], f2 = (float)v[2], f3 = (float)v[3];
        f16x4 o; o[0] = (_Float16)r0; o[1] = (_Float16)r1; o[2] = (_Float16)r2; o[3] = (_Float16)r3;
        *(f16x4*)ptr = o;
        float P = sp_[c];
        r0 = fmaf(r0, P, f0); r1 = fmaf(r1, P, f1);
        r2 = fmaf(r2, P, f2); r3 = fmaf(r3, P, f3);
    }
}

// ---------------- K4cC: per-chunk y via SSD GEMMs ----------------
__global__ __launch_bounds__(256) void k4cC(
    const _Float16* __restrict__ bcNat, const _Float16* __restrict__ xsT,
    const _Float16* __restrict__ sinit, const float* __restrict__ dtp,
    const float* __restrict__ ldA, const float* __restrict__ Dp,
    _Float16* __restrict__ yB)
{
    __shared__ char smem[(64*136 + 64*136 + 128*72 + 4*16*72) * 2 + 640];
    _Float16* sC  = (_Float16*)smem;
    _Float16* sB  = sC + 64 * 136;
    _Float16* sXT = sB + 64 * 136;
    _Float16* sM  = sXT + 128 * 72;
    float* scum = (float*)(sM + 4 * 16 * 72);
    float* sdt  = scum + 64;
    _Float16* sIni = sB;
    _Float16* sY  = sC;

    const int tid = threadIdx.x;
    const int lane = tid & 63;
    const int wv = tid >> 6;
    const int quad = lane >> 4, l15 = lane & 15;
    const int c = blockIdx.x & 63;
    const int h = (blockIdx.x >> 6) & 7;
    const int b = blockIdx.x >> 9;
    const int bh = b * NHEADS + h;
    const size_t mbase = (size_t)b * LSEQ + c * QC;
    const float Dh = Dp[h];

    if (tid < 64) {
        size_t gi = (mbase + tid) * NHEADS + h;
        float ld = ldA[gi];
        float dtv = dtp[gi];
        float cum = ld;
        #pragma unroll
        for (int off = 1; off < 64; off <<= 1) {
            float v = __shfl_up(cum, off);
            if (tid >= off) cum += v;
        }
        scum[tid] = cum;
        sdt[tid] = dtv;
    }
    #pragma unroll
    for (int k = 0; k < 4; ++k) {
        int idx = k * 256 + tid;
        int t = idx >> 4, g = idx & 15;
        const _Float16* row = bcNat + (mbase + t) * 256;
        *(int4*)&sB[t * 136 + g * 8] = *(const int4*)&row[g * 8];
        *(int4*)&sC[t * 136 + g * 8] = *(const int4*)&row[128 + g * 8];
        int idx2 = k * 256 + tid;
        int p = idx2 >> 3, g2 = idx2 & 7;
        *(int4*)&sXT[p * 72 + g2 * 8] =
            *(const int4*)&xsT[((size_t)b * D_INNER + h * HEADDIM + p) * LSEQ + c * QC + g2 * 8];
    }
    __syncthreads();

    // G = C @ B^T
    f32x4 g[4];
    #pragma unroll
    for (int j = 0; j < 4; ++j) g[j] = (f32x4){0.f, 0.f, 0.f, 0.f};
    #pragma unroll
    for (int kk = 0; kk < 4; ++kk) {
        f16x8 af = *(const f16x8*)&sC[(wv * 16 + l15) * 136 + kk * 32 + quad * 8];
        #pragma unroll
        for (int tt = 0; tt < 4; ++tt) {
            f16x8 bf_ = *(const f16x8*)&sB[(tt * 16 + l15) * 136 + kk * 32 + quad * 8];
            g[tt] = __builtin_amdgcn_mfma_f32_16x16x32_f16(af, bf_, g[tt], 0, 0, 0);
        }
    }
    _Float16* sMw = sM + wv * 16 * 72;
    #pragma unroll
    for (int tt = 0; tt < 4; ++tt) {
        int tau = tt * 16 + l15;
        #pragma unroll
        for (int reg = 0; reg < 4; ++reg) {
            int trow = quad * 4 + reg;
            int tglob = wv * 16 + trow;
            float mval;
            if (tau > tglob) mval = 0.f;
            else if (tau == tglob) mval = g[tt][reg] * sdt[tau] + Dh;
            else mval = g[tt][reg] * expf(scum[tglob] - scum[tau]) * sdt[tau];
            sMw[trow * 72 + tau] = (_Float16)mval;
        }
    }
    asm volatile("s_waitcnt lgkmcnt(0)" ::: "memory");

    // Y1 = M @ X^T
    f32x4 y[8];
    #pragma unroll
    for (int j = 0; j < 8; ++j) y[j] = (f32x4){0.f, 0.f, 0.f, 0.f};
    #pragma unroll
    for (int kk = 0; kk < 2; ++kk) {
        f16x8 af = *(const f16x8*)&sMw[l15 * 72 + kk * 32 + quad * 8];
        #pragma unroll
        for (int pi = 0; pi < 8; ++pi) {
            f16x8 bf_ = *(const f16x8*)&sXT[(pi * 16 + l15) * 72 + kk * 32 + quad * 8];
            y[pi] = __builtin_amdgcn_mfma_f32_16x16x32_f16(af, bf_, y[pi], 0, 0, 0);
        }
    }
    __syncthreads();
    {
        const _Float16* sg = sinit + ((size_t)bh * NCH + c) * (HEADDIM * D_STATE);
        #pragma unroll
        for (int k = 0; k < 8; ++k) {
            int idx = k * 256 + tid;
            int p = idx >> 4, gg = idx & 15;
            *(int4*)&sIni[p * 136 + gg * 8] = *(const int4*)&sg[p * 128 + gg * 8];
        }
    }
    __syncthreads();
    // Y2 += (e^cum * C) @ s_init^T
    {
        float ea = expf(scum[wv * 16 + l15]);
        #pragma unroll
        for (int kk = 0; kk < 4; ++kk) {
            f16x8 cf = *(const f16x8*)&sC[(wv * 16 + l15) * 136 + kk * 32 + quad * 8];
            f16x8 af;
            #pragma unroll
            for (int j = 0; j < 8; ++j) af[j] = (_Float16)((float)cf[j] * ea);
            #pragma unroll
            for (int pi = 0; pi < 8; ++pi) {
                f16x8 bf_ = *(const f16x8*)&sIni[(pi * 16 + l15) * 136 + kk * 32 + quad * 8];
                y[pi] = __builtin_amdgcn_mfma_f32_16x16x32_f16(af, bf_, y[pi], 0, 0, 0);
            }
        }
    }
    __syncthreads();
    #pragma unroll
    for (int pi = 0; pi < 8; ++pi)
        #pragma unroll
        for (int reg = 0; reg < 4; ++reg) {
            int trow = wv * 16 + quad * 4 + reg;
            int p = pi * 16 + l15;
            sY[trow * 136 + p] = (_Float16)y[pi][reg];
        }
    __syncthreads();
    #pragma unroll
    for (int k = 0; k < 4; ++k) {
        int idx = k * 256 + tid;
        int t = idx >> 4, gg = idx & 15;
        int4 v = *(const int4*)&sY[t * 136 + gg * 8];
        *(int4*)&yB[(mbase + t) * D_INNER + h * HEADDIM + gg * 8] = v;
    }
}

// ---------------- K5: y *= silu(z); RMSNorm * norm_w -> bf16 (in place over yB) ----------------
__global__ __launch_bounds__(256) void k5_norm(
    const _Float16* __restrict__ yB, const _Float16* __restrict__ zh,
    const float* __restrict__ nw, ushort* __restrict__ ybB)
{
    const int m = blockIdx.x;
    const int tid = threadIdx.x;
    const size_t off = (size_t)m * D_INNER + tid * 4;
    f16x4 yv = *(const f16x4*)&yB[off];
    f16x4 zv = *(const f16x4*)&zh[off];
    float4 gv;
    {
        float z0 = (float)zv[0], z1 = (float)zv[1], z2 = (float)zv[2], z3 = (float)zv[3];
        gv.x = (float)yv[0] * (z0 / (1.f + expf(-z0)));
        gv.y = (float)yv[1] * (z1 / (1.f + expf(-z1)));
        gv.z = (float)yv[2] * (z2 / (1.f + expf(-z2)));
        gv.w = (float)yv[3] * (z3 / (1.f + expf(-z3)));
    }
    float ss = gv.x*gv.x + gv.y*gv.y + gv.z*gv.z + gv.w*gv.w;
    #pragma unroll
    for (int mask = 1; mask <= 32; mask <<= 1) ss += __shfl_xor(ss, mask);
    __shared__ float red[4];
    if ((tid & 63) == 0) red[tid >> 6] = ss;
    __syncthreads();
    float tot = red[0] + red[1] + red[2] + red[3];
    float scale = rsqrtf(tot * (1.f / 1024.f) + 1e-5f);
    float4 w4 = *(const float4*)(nw + tid * 4);
    ushort4 ob;
    ob.x = f2bf(gv.x * scale * w4.x);
    ob.y = f2bf(gv.y * scale * w4.y);
    ob.z = f2bf(gv.z * scale * w4.z);
    ob.w = f2bf(gv.w * scale * w4.w);
    *(ushort4*)(ybB + off) = ob;
}

// ---------------- K6: out_proj GEMM bf16 MFMA + residual, BK=32 global_load_lds ----------------
__global__ __launch_bounds__(256) void k6_mfma(
    const ushort* __restrict__ A, const ushort* __restrict__ B,
    const float* __restrict__ x, float* __restrict__ out)
{
    __shared__ ushort sA[128 * 32];
    __shared__ ushort sB[128 * 32];
    const int tid = threadIdx.x;
    const int lane = tid & 63;
    const int wv = tid >> 6;
    const int wm = (wv & 1) * 64, wn = (wv >> 1) * 64;
    const int m0 = blockIdx.x * 128;
    const int n0 = blockIdx.y * 128;

    f32x4 acc[4][4];
    #pragma unroll
    for (int i = 0; i < 4; ++i)
        #pragma unroll
        for (int j = 0; j < 4; ++j) acc[i][j] = (f32x4){0.f, 0.f, 0.f, 0.f};

    const int r0 = tid >> 2, c0 = tid & 3, k80 = c0 ^ ((r0 >> 1) & 3);
    const int s1_ = tid + 256;
    const int r1 = s1_ >> 2, c1 = s1_ & 3, k81 = c1 ^ ((r1 >> 1) & 3);
    const int quad = lane >> 4, col = lane & 15;
    ushort* lA0 = sA + (size_t)(wv * 64) * 8;
    ushort* lA1 = sA + (size_t)(256 + wv * 64) * 8;
    ushort* lB0 = sB + (size_t)(wv * 64) * 8;
    ushort* lB1 = sB + (size_t)(256 + wv * 64) * 8;

    for (int kb = 0; kb < D_INNER; kb += 32) {
        gload_lds16(A + (size_t)(m0 + r0) * D_INNER + kb + k80 * 8, lA0);
        gload_lds16(A + (size_t)(m0 + r1) * D_INNER + kb + k81 * 8, lA1);
        gload_lds16(B + (size_t)(n0 + r0) * D_INNER + kb + k80 * 8, lB0);
        gload_lds16(B + (size_t)(n0 + r1) * D_INNER + kb + k81 * 8, lB1);
        __syncthreads();
        bf16x8 af[4], bf_[4];
        #pragma unroll
        for (int mi = 0; mi < 4; ++mi) {
            int m = wm + mi * 16 + col;
            int ch = quad ^ ((m >> 1) & 3);
            af[mi] = *(const bf16x8*)&sA[m * 32 + ch * 8];
        }
        #pragma unroll
        for (int ni = 0; ni < 4; ++ni) {
            int n = wn + ni * 16 + col;
            int ch = quad ^ ((n >> 1) & 3);
            bf_[ni] = *(const bf16x8*)&sB[n * 32 + ch * 8];
        }
        #pragma unroll
        for (int mi = 0; mi < 4; ++mi)
            #pragma unroll
            for (int ni = 0; ni < 4; ++ni)
                acc[mi][ni] = __builtin_amdgcn_mfma_f32_16x16x32_bf16(af[mi], bf_[ni], acc[mi][ni], 0, 0, 0);
        __syncthreads();
    }

    #pragma unroll
    for (int mi = 0; mi < 4; ++mi) {
        #pragma unroll
        for (int ni = 0; ni < 4; ++ni) {
            int mm = n0 + wn + ni * 16 + col;
            int b = mm >> 12, l = mm & 4095;
            #pragma unroll
            for (int reg = 0; reg < 4; ++reg) {
                int d = m0 + wm + mi * 16 + quad * 4 + reg;
                size_t o = ((size_t)(b * DIMC + d) << 12) + l;
                out[o] = acc[mi][ni][reg] + x[o];
            }
        }
    }
}

extern "C" void kernel_launch(void* const* d_in, const int* in_sizes, int n_in,
                              void* d_out, int out_size, void* d_ws, size_t ws_size,
                              hipStream_t stream) {
    const float* x          = (const float*)d_in[0];
    const float* in_proj_w  = (const float*)d_in[1];
    const float* conv_w     = (const float*)d_in[2];
    const float* conv_b     = (const float*)d_in[3];
    const float* dt_bias    = (const float*)d_in[4];
    const float* A_log      = (const float*)d_in[5];
    const float* D_param    = (const float*)d_in[6];
    const float* norm_w     = (const float*)d_in[7];
    const float* out_proj_w = (const float*)d_in[8];
    float* out = (float*)d_out;

    float* ws = (float*)d_ws;
    float* zbuf = ws;                                      // region A: 16,777,216 f32
    _Float16* zh = (_Float16*)zbuf;                        // z stored f16
    float* regB = zbuf + (size_t)16777216;
    _Float16* xbcPre = (_Float16*)regB;                    // 16384x1280 f16
    _Float16* yB     = (_Float16*)regB;                    // 16384x1024 f16 (after k3)
    float* dtb  = regB + (size_t)10485760;
    float* dtp  = dtb + 131072;
    float* ldA  = dtp + 131072;
    float* Pbuf = ldA + 131072;                            // 2048
    float* regD = Pbuf + 2048;
    ushort* xT_k1 = (ushort*)regD;                         // 16384x512 bf16
    ushort* Wb    = xT_k1 + (size_t)BLTOT * DIMC;          // 2432x512 bf16
    _Float16* ST  = (_Float16*)regD;                       // 32x64x128x128 f16 (after k1)
    float* regE = regD + (size_t)16777216;
    _Float16* xsT   = (_Float16*)regE;                     // 4x1024x4096 f16
    _Float16* BT    = xsT + (size_t)BSZ * D_INNER * LSEQ;  // 4x128x4096 f16
    _Float16* bcNat = BT + (size_t)BSZ * D_STATE * LSEQ;   // 16384x256 f16
    ushort* woutB   = (ushort*)(bcNat + (size_t)BLTOT * 256);  // 512x1024 bf16 (independent slot)

    k0_prep<<<dim3(9920), dim3(256), 0, stream>>>(x, xT_k1, in_proj_w, Wb, out_proj_w, woutB);
    k1_mfma<<<dim3(128, 19), dim3(256), 0, stream>>>(xT_k1, Wb, zh, xbcPre, dtp, ldA, dt_bias, A_log);
    k3_conv<<<dim3(20480), dim3(256), 0, stream>>>(xbcPre, conv_w, conv_b, xsT, bcNat, BT);
    k4aA<<<dim3(2048), dim3(256), 0, stream>>>(xsT, BT, dtp, ldA, ST, Pbuf);
    k4bB<<<dim3(512), dim3(256), 0, stream>>>(ST, Pbuf);
    k4cC<<<dim3(2048), dim3(256), 0, stream>>>(bcNat, xsT, ST, dtp, ldA, D_param, yB);
    k5_norm<<<dim3(BLTOT), dim3(256), 0, stream>>>(yB, zh, norm_w, (ushort*)yB);
    k6_mfma<<<dim3(4, 128), dim3(256), 0, stream>>>(woutB, (ushort*)yB, x, out);
}

// Round 11
// 390.699 us; speedup vs baseline: 1.4338x; 1.0556x over previous
//
#include <hip/hip_runtime.h>
#include <cstdint>
#include <cstddef>

#define DIMC     512
#define D_INNER  1024
#define HEADDIM  128
#define NHEADS   8
#define D_STATE  128
#define CONV_DIM 1280
#define D_IN_PROJ 2312
#define NPAD     2432
#define BSZ      4
#define LSEQ     4096
#define BLTOT    (BSZ*LSEQ)   // 16384
#define QC       64           // SSD chunk length
#define NCH      (LSEQ/QC)    // 64 chunks

typedef short bf16x8 __attribute__((ext_vector_type(8)));
typedef float f32x4  __attribute__((ext_vector_type(4)));
typedef _Float16 f16x8 __attribute__((ext_vector_type(8)));
typedef _Float16 f16x4 __attribute__((ext_vector_type(4)));

__device__ inline ushort f2bf(float f) {
    uint32_t u = __float_as_uint(f);
    uint32_t r = (u + 0x7FFFu + ((u >> 16) & 1u)) >> 16;
    return (ushort)r;
}

// async global->LDS, 16B per lane; lds base must be wave-uniform
__device__ __forceinline__ void gload_lds16(const void* g, void* l) {
    __builtin_amdgcn_global_load_lds(
        (const __attribute__((address_space(1))) void*)g,
        (__attribute__((address_space(3))) void*)l,
        16, 0, 0);
}

// ---------------- K0: fused prep. blocks [0,8192): x transpose->bf16; [8192,9408): Wb; [9408,9920): wout ----------------
__global__ __launch_bounds__(256) void k0_prep(
    const float* __restrict__ x, ushort* __restrict__ xT,
    const float* __restrict__ Win, ushort* __restrict__ Wb,
    const float* __restrict__ Wout, ushort* __restrict__ WoutB)
{
    const int bx = blockIdx.x;
    if (bx < 8192) {
        __shared__ float t[32][33];
        const int lt = bx & 127, dt = (bx >> 7) & 15, b = bx >> 11;
        const int r = threadIdx.x >> 5, c = threadIdx.x & 31;
        #pragma unroll
        for (int i = 0; i < 4; ++i) {
            int d = dt * 32 + r + i * 8;
            t[r + i * 8][c] = x[((size_t)(b * DIMC + d) << 12) + lt * 32 + c];
        }
        __syncthreads();
        #pragma unroll
        for (int i = 0; i < 4; ++i) {
            int l = lt * 32 + r + i * 8;
            xT[((size_t)(b * LSEQ + l)) * DIMC + dt * 32 + c] = f2bf(t[c][r + i * 8]);
        }
    } else if (bx < 9408) {
        int i4 = ((bx - 8192) * 256 + threadIdx.x) * 4;   // NPAD*512
        int e = i4 >> 9;
        ushort4 o;
        if (e < D_IN_PROJ) {
            float4 v = *(const float4*)(Win + (size_t)e * DIMC + (i4 & 511));
            o.x = f2bf(v.x); o.y = f2bf(v.y); o.z = f2bf(v.z); o.w = f2bf(v.w);
        } else { o.x = o.y = o.z = o.w = 0; }
        *(ushort4*)(Wb + i4) = o;
    } else {
        int i4 = ((bx - 9408) * 256 + threadIdx.x) * 4;   // 512*1024
        float4 v = *(const float4*)(Wout + i4);
        ushort4 o;
        o.x = f2bf(v.x); o.y = f2bf(v.y); o.z = f2bf(v.z); o.w = f2bf(v.w);
        *(ushort4*)(WoutB + i4) = o;
    }
}

// ---------------- K1: in_proj GEMM, bf16 MFMA, BK=32 global_load_lds (R7-exact structure) ----------------
__global__ __launch_bounds__(256) void k1_mfma(
    const ushort* __restrict__ A, const ushort* __restrict__ B,
    _Float16* __restrict__ zh, _Float16* __restrict__ xbcPre, float* __restrict__ dtb)
{
    __shared__ ushort sA[128 * 32];
    __shared__ ushort sB[128 * 32];
    const int tid = threadIdx.x;
    const int lane = tid & 63;
    const int wv = tid >> 6;
    const int wm = (wv & 1) * 64, wn = (wv >> 1) * 64;
    const int m0 = blockIdx.x * 128;
    const int n0 = blockIdx.y * 128;

    f32x4 acc[4][4];
    #pragma unroll
    for (int i = 0; i < 4; ++i)
        #pragma unroll
        for (int j = 0; j < 4; ++j) acc[i][j] = (f32x4){0.f, 0.f, 0.f, 0.f};

    // slot s holds row r=s>>2, k-chunk k8=(s&3)^((r>>1)&3); slots: tid and tid+256
    const int r0 = tid >> 2, c0 = tid & 3, k80 = c0 ^ ((r0 >> 1) & 3);
    const int s1_ = tid + 256;
    const int r1 = s1_ >> 2, c1 = s1_ & 3, k81 = c1 ^ ((r1 >> 1) & 3);
    const int quad = lane >> 4, col = lane & 15;
    // wave-uniform LDS bases (ushort units): slot*8
    ushort* lA0 = sA + (size_t)(wv * 64) * 8;
    ushort* lA1 = sA + (size_t)(256 + wv * 64) * 8;
    ushort* lB0 = sB + (size_t)(wv * 64) * 8;
    ushort* lB1 = sB + (size_t)(256 + wv * 64) * 8;

    for (int kb = 0; kb < DIMC; kb += 32) {
        gload_lds16(A + (size_t)(m0 + r0) * DIMC + kb + k80 * 8, lA0);
        gload_lds16(A + (size_t)(m0 + r1) * DIMC + kb + k81 * 8, lA1);
        gload_lds16(B + (size_t)(n0 + r0) * DIMC + kb + k80 * 8, lB0);
        gload_lds16(B + (size_t)(n0 + r1) * DIMC + kb + k81 * 8, lB1);
        __syncthreads();
        bf16x8 af[4], bf_[4];
        #pragma unroll
        for (int mi = 0; mi < 4; ++mi) {
            int m = wm + mi * 16 + col;
            int ch = quad ^ ((m >> 1) & 3);
            af[mi] = *(const bf16x8*)&sA[m * 32 + ch * 8];
        }
        #pragma unroll
        for (int ni = 0; ni < 4; ++ni) {
            int n = wn + ni * 16 + col;
            int ch = quad ^ ((n >> 1) & 3);
            bf_[ni] = *(const bf16x8*)&sB[n * 32 + ch * 8];
        }
        #pragma unroll
        for (int mi = 0; mi < 4; ++mi)
            #pragma unroll
            for (int ni = 0; ni < 4; ++ni)
                acc[mi][ni] = __builtin_amdgcn_mfma_f32_16x16x32_bf16(af[mi], bf_[ni], acc[mi][ni], 0, 0, 0);
        __syncthreads();
    }

    #pragma unroll
    for (int mi = 0; mi < 4; ++mi) {
        #pragma unroll
        for (int ni = 0; ni < 4; ++ni) {
            int e = n0 + wn + ni * 16 + col;
            #pragma unroll
            for (int reg = 0; reg < 4; ++reg) {
                int m = m0 + wm + mi * 16 + quad * 4 + reg;
                float v = acc[mi][ni][reg];
                if (e < D_INNER)                  zh[(size_t)m * D_INNER + e] = (_Float16)v;
                else if (e < D_INNER + CONV_DIM)  xbcPre[(size_t)m * CONV_DIM + (e - D_INNER)] = (_Float16)v;
                else if (e < D_IN_PROJ)           dtb[(size_t)m * NHEADS + (e - (D_INNER + CONV_DIM))] = v;
            }
        }
    }
}

// ---------------- K2: softplus(dt + bias) -> dtp; ldA = dtp * (-exp(A_log)) ----------------
__global__ __launch_bounds__(256) void k2_dt(
    const float* __restrict__ dtb, const float* __restrict__ dt_bias,
    const float* __restrict__ A_log, float* __restrict__ dtp, float* __restrict__ ldA)
{
    int idx = blockIdx.x * 256 + threadIdx.x;
    if (idx >= BLTOT * NHEADS) return;
    int h = idx & 7;
    float v = dtb[idx] + dt_bias[h];
    float sp = (v > 20.f) ? v : log1pf(expf(v));
    dtp[idx] = sp;
    ldA[idx] = sp * (-expf(A_log[h]));
}

// ---------------- K3: fused conv+silu. blocks [0,16384): x-channels -> xsT; [16384,20480): B/C channels ----------------
__global__ __launch_bounds__(256) void k3_conv(
    const _Float16* __restrict__ xbcPre, const float* __restrict__ cw,
    const float* __restrict__ cb, _Float16* __restrict__ xsT,
    _Float16* __restrict__ bcNat, _Float16* __restrict__ BT)
{
    __shared__ _Float16 tT[32][36];
    const int tid = threadIdx.x;
    const int tq = tid >> 3, cg = tid & 7;
    if (blockIdx.x < 16384) {
        const int bx = blockIdx.x;
        const int ct = bx & 31, tt = (bx >> 5) & 127, b = bx >> 12;
        const int t0 = tt * 32, c0 = ct * 32;
        const int t = t0 + tq;
        const int c = c0 + cg * 4;
        const int m = b * LSEQ + t;

        float acc[4] = {cb[c], cb[c + 1], cb[c + 2], cb[c + 3]};
        #pragma unroll
        for (int j = 0; j < 4; ++j) {
            if (t - j >= 0) {
                f16x4 xv = *(const f16x4*)&xbcPre[(size_t)(m - j) * CONV_DIM + c];
                #pragma unroll
                for (int i = 0; i < 4; ++i)
                    acc[i] = fmaf((float)xv[i], cw[(c + i) * 4 + (3 - j)], acc[i]);
            }
        }
        #pragma unroll
        for (int i = 0; i < 4; ++i) {
            float s = acc[i] / (1.f + expf(-acc[i]));
            tT[cg * 4 + i][tq] = (_Float16)s;
        }
        __syncthreads();
        const int r = tid >> 3, g = tid & 7;
        f16x4 o = *(const f16x4*)&tT[r][g * 4];
        *(f16x4*)&xsT[((size_t)b * D_INNER + c0 + r) * LSEQ + t0 + g * 4] = o;
    } else {
        const int bx = blockIdx.x - 16384;
        const int ct = bx & 7, tt = (bx >> 3) & 127, b = bx >> 10;
        const int t0 = tt * 32, c0 = ct * 32;
        const int t = t0 + tq;
        const int ca = 1024 + c0 + cg * 4;
        const int m = b * LSEQ + t;

        float acc[4] = {cb[ca], cb[ca + 1], cb[ca + 2], cb[ca + 3]};
        #pragma unroll
        for (int j = 0; j < 4; ++j) {
            if (t - j >= 0) {
                f16x4 xv = *(const f16x4*)&xbcPre[(size_t)(m - j) * CONV_DIM + ca];
                #pragma unroll
                for (int i = 0; i < 4; ++i)
                    acc[i] = fmaf((float)xv[i], cw[(ca + i) * 4 + (3 - j)], acc[i]);
            }
        }
        f16x4 nat;
        #pragma unroll
        for (int i = 0; i < 4; ++i) {
            float s = acc[i] / (1.f + expf(-acc[i]));
            nat[i] = (_Float16)s;
            tT[cg * 4 + i][tq] = nat[i];
        }
        *(f16x4*)&bcNat[(size_t)m * 256 + c0 + cg * 4] = nat;
        if (ct < 4) {
            __syncthreads();
            const int r = tid >> 3, g = tid & 7;
            f16x4 o = *(const f16x4*)&tT[r][g * 4];
            *(f16x4*)&BT[((size_t)b * D_STATE + c0 + r) * LSEQ + t0 + g * 4] = o;
        }
    }
}

// ---------------- K4aA: per-chunk local state GEMM ----------------
__global__ __launch_bounds__(256) void k4aA(
    const _Float16* __restrict__ xsT, const _Float16* __restrict__ BT,
    const float* __restrict__ dtp, const float* __restrict__ ldA,
    _Float16* __restrict__ ST, float* __restrict__ Pbuf)
{
    __shared__ char smem[128 * 72 * 2 * 2 + 512];
    _Float16* sXTs = (_Float16*)smem;
    _Float16* sBT  = sXTs + 128 * 72;
    float* sW = (float*)(sBT + 128 * 72);
    _Float16* sOut = sXTs;

    const int tid = threadIdx.x;
    const int lane = tid & 63;
    const int wv = tid >> 6;
    const int quad = lane >> 4, l15 = lane & 15;
    const int c = blockIdx.x & 63;
    const int h = (blockIdx.x >> 6) & 7;
    const int b = blockIdx.x >> 9;
    const int bh = b * NHEADS + h;
    const size_t mbase = (size_t)b * LSEQ + c * QC;

    if (tid < 64) {
        size_t gi = (mbase + tid) * NHEADS + h;
        float ld = ldA[gi];
        float dtv = dtp[gi];
        float cum = ld;
        #pragma unroll
        for (int off = 1; off < 64; off <<= 1) {
            float v = __shfl_up(cum, off);
            if (tid >= off) cum += v;
        }
        float cum63 = __shfl(cum, 63);
        sW[tid] = expf(cum63 - cum) * dtv;
        if (tid == 63) Pbuf[bh * NCH + c] = expf(cum63);
    }
    __syncthreads();

    #pragma unroll
    for (int k = 0; k < 4; ++k) {
        int idx = k * 256 + tid;
        int row = idx >> 3, g = idx & 7;
        int t0 = g * 8;
        f16x8 hv = *(const f16x8*)&xsT[((size_t)b * D_INNER + h * HEADDIM + row) * LSEQ + c * QC + t0];
        f16x8 sv;
        #pragma unroll
        for (int j = 0; j < 8; ++j) sv[j] = (_Float16)((float)hv[j] * sW[t0 + j]);
        *(f16x8*)&sXTs[row * 72 + t0] = sv;
        int4 bv = *(const int4*)&BT[((size_t)b * D_STATE + row) * LSEQ + c * QC + t0];
        *(int4*)&sBT[row * 72 + t0] = bv;
    }
    __syncthreads();

    f32x4 acc[2][8];
    #pragma unroll
    for (int i = 0; i < 2; ++i)
        #pragma unroll
        for (int j = 0; j < 8; ++j) acc[i][j] = (f32x4){0.f, 0.f, 0.f, 0.f};

    #pragma unroll
    for (int kk = 0; kk < 2; ++kk) {
        f16x8 af[2];
        #pragma unroll
        for (int mi = 0; mi < 2; ++mi)
            af[mi] = *(const f16x8*)&sXTs[(wv * 32 + mi * 16 + l15) * 72 + kk * 32 + quad * 8];
        #pragma unroll
        for (int ni = 0; ni < 8; ++ni) {
            f16x8 bf_ = *(const f16x8*)&sBT[(ni * 16 + l15) * 72 + kk * 32 + quad * 8];
            #pragma unroll
            for (int mi = 0; mi < 2; ++mi)
                acc[mi][ni] = __builtin_amdgcn_mfma_f32_16x16x32_f16(af[mi], bf_, acc[mi][ni], 0, 0, 0);
        }
    }
    __syncthreads();
    #pragma unroll
    for (int mi = 0; mi < 2; ++mi)
        #pragma unroll
        for (int ni = 0; ni < 8; ++ni)
            #pragma unroll
            for (int reg = 0; reg < 4; ++reg) {
                int p = wv * 32 + mi * 16 + quad * 4 + reg;
                int n = ni * 16 + l15;
                sOut[p * 136 + n] = (_Float16)acc[mi][ni][reg];
            }
    __syncthreads();
    _Float16* stg = ST + ((size_t)bh * NCH + c) * (HEADDIM * D_STATE);
    #pragma unroll
    for (int k = 0; k < 8; ++k) {
        int idx = k * 256 + tid;
        int row = idx >> 4, g = idx & 15;
        int4 v = *(const int4*)&sOut[row * 136 + g * 8];
        *(int4*)&stg[row * 128 + g * 8] = v;
    }
}

// ---------------- K4bB: 64-chunk state prefix (in place) ----------------
__global__ __launch_bounds__(256) void k4bB(_Float16* __restrict__ ST, const float* __restrict__ Pbuf)
{
    __shared__ float sp_[NCH];
    const int bh = blockIdx.x >> 4;
    const int seg = blockIdx.x & 15;
    const int tid = threadIdx.x;
    if (tid < NCH) sp_[tid] = Pbuf[bh * NCH + tid];
    __syncthreads();
    const int e = seg * 1024 + tid * 4;
    float r0 = 0.f, r1 = 0.f, r2 = 0.f, r3 = 0.f;
    for (int c = 0; c < NCH; ++c) {
        _Float16* ptr = ST + ((size_t)bh * NCH + c) * (HEADDIM * D_STATE) + e;
        f16x4 v = *(const f16x4*)ptr;
        float f0 = (float)v[0], f1 = (float)v[1], f2 = (float)v[2], f3 = (float)v[3];
        f16x4 o; o[0] = (_Float16)r0; o[1] = (_Float16)r1; o[2] = (_Float16)r2; o[3] = (_Float16)r3;
        *(f16x4*)ptr = o;
        float P = sp_[c];
        r0 = fmaf(r0, P, f0); r1 = fmaf(r1, P, f1);
        r2 = fmaf(r2, P, f2); r3 = fmaf(r3, P, f3);
    }
}

// ---------------- K4cC: per-chunk y via SSD GEMMs ----------------
__global__ __launch_bounds__(256) void k4cC(
    const _Float16* __restrict__ bcNat, const _Float16* __restrict__ xsT,
    const _Float16* __restrict__ sinit, const float* __restrict__ dtp,
    const float* __restrict__ ldA, const float* __restrict__ Dp,
    _Float16* __restrict__ yB)
{
    __shared__ char smem[(64*136 + 64*136 + 128*72 + 4*16*72) * 2 + 640];
    _Float16* sC  = (_Float16*)smem;
    _Float16* sB  = sC + 64 * 136;
    _Float16* sXT = sB + 64 * 136;
    _Float16* sM  = sXT + 128 * 72;
    float* scum = (float*)(sM + 4 * 16 * 72);
    float* sdt  = scum + 64;
    _Float16* sIni = sB;
    _Float16* sY  = sC;

    const int tid = threadIdx.x;
    const int lane = tid & 63;
    const int wv = tid >> 6;
    const int quad = lane >> 4, l15 = lane & 15;
    const int c = blockIdx.x & 63;
    const int h = (blockIdx.x >> 6) & 7;
    const int b = blockIdx.x >> 9;
    const int bh = b * NHEADS + h;
    const size_t mbase = (size_t)b * LSEQ + c * QC;
    const float Dh = Dp[h];

    if (tid < 64) {
        size_t gi = (mbase + tid) * NHEADS + h;
        float ld = ldA[gi];
        float dtv = dtp[gi];
        float cum = ld;
        #pragma unroll
        for (int off = 1; off < 64; off <<= 1) {
            float v = __shfl_up(cum, off);
            if (tid >= off) cum += v;
        }
        scum[tid] = cum;
        sdt[tid] = dtv;
    }
    #pragma unroll
    for (int k = 0; k < 4; ++k) {
        int idx = k * 256 + tid;
        int t = idx >> 4, g = idx & 15;
        const _Float16* row = bcNat + (mbase + t) * 256;
        *(int4*)&sB[t * 136 + g * 8] = *(const int4*)&row[g * 8];
        *(int4*)&sC[t * 136 + g * 8] = *(const int4*)&row[128 + g * 8];
        int idx2 = k * 256 + tid;
        int p = idx2 >> 3, g2 = idx2 & 7;
        *(int4*)&sXT[p * 72 + g2 * 8] =
            *(const int4*)&xsT[((size_t)b * D_INNER + h * HEADDIM + p) * LSEQ + c * QC + g2 * 8];
    }
    __syncthreads();

    // G = C @ B^T
    f32x4 g[4];
    #pragma unroll
    for (int j = 0; j < 4; ++j) g[j] = (f32x4){0.f, 0.f, 0.f, 0.f};
    #pragma unroll
    for (int kk = 0; kk < 4; ++kk) {
        f16x8 af = *(const f16x8*)&sC[(wv * 16 + l15) * 136 + kk * 32 + quad * 8];
        #pragma unroll
        for (int tt = 0; tt < 4; ++tt) {
            f16x8 bf_ = *(const f16x8*)&sB[(tt * 16 + l15) * 136 + kk * 32 + quad * 8];
            g[tt] = __builtin_amdgcn_mfma_f32_16x16x32_f16(af, bf_, g[tt], 0, 0, 0);
        }
    }
    _Float16* sMw = sM + wv * 16 * 72;
    #pragma unroll
    for (int tt = 0; tt < 4; ++tt) {
        int tau = tt * 16 + l15;
        #pragma unroll
        for (int reg = 0; reg < 4; ++reg) {
            int trow = quad * 4 + reg;
            int tglob = wv * 16 + trow;
            float mval;
            if (tau > tglob) mval = 0.f;
            else if (tau == tglob) mval = g[tt][reg] * sdt[tau] + Dh;
            else mval = g[tt][reg] * expf(scum[tglob] - scum[tau]) * sdt[tau];
            sMw[trow * 72 + tau] = (_Float16)mval;
        }
    }
    asm volatile("s_waitcnt lgkmcnt(0)" ::: "memory");

    // Y1 = M @ X^T
    f32x4 y[8];
    #pragma unroll
    for (int j = 0; j < 8; ++j) y[j] = (f32x4){0.f, 0.f, 0.f, 0.f};
    #pragma unroll
    for (int kk = 0; kk < 2; ++kk) {
        f16x8 af = *(const f16x8*)&sMw[l15 * 72 + kk * 32 + quad * 8];
        #pragma unroll
        for (int pi = 0; pi < 8; ++pi) {
            f16x8 bf_ = *(const f16x8*)&sXT[(pi * 16 + l15) * 72 + kk * 32 + quad * 8];
            y[pi] = __builtin_amdgcn_mfma_f32_16x16x32_f16(af, bf_, y[pi], 0, 0, 0);
        }
    }
    __syncthreads();
    {
        const _Float16* sg = sinit + ((size_t)bh * NCH + c) * (HEADDIM * D_STATE);
        #pragma unroll
        for (int k = 0; k < 8; ++k) {
            int idx = k * 256 + tid;
            int p = idx >> 4, gg = idx & 15;
            *(int4*)&sIni[p * 136 + gg * 8] = *(const int4*)&sg[p * 128 + gg * 8];
        }
    }
    __syncthreads();
    // Y2 += (e^cum * C) @ s_init^T
    {
        float ea = expf(scum[wv * 16 + l15]);
        #pragma unroll
        for (int kk = 0; kk < 4; ++kk) {
            f16x8 cf = *(const f16x8*)&sC[(wv * 16 + l15) * 136 + kk * 32 + quad * 8];
            f16x8 af;
            #pragma unroll
            for (int j = 0; j < 8; ++j) af[j] = (_Float16)((float)cf[j] * ea);
            #pragma unroll
            for (int pi = 0; pi < 8; ++pi) {
                f16x8 bf_ = *(const f16x8*)&sIni[(pi * 16 + l15) * 136 + kk * 32 + quad * 8];
                y[pi] = __builtin_amdgcn_mfma_f32_16x16x32_f16(af, bf_, y[pi], 0, 0, 0);
            }
        }
    }
    __syncthreads();
    #pragma unroll
    for (int pi = 0; pi < 8; ++pi)
        #pragma unroll
        for (int reg = 0; reg < 4; ++reg) {
            int trow = wv * 16 + quad * 4 + reg;
            int p = pi * 16 + l15;
            sY[trow * 136 + p] = (_Float16)y[pi][reg];
        }
    __syncthreads();
    #pragma unroll
    for (int k = 0; k < 4; ++k) {
        int idx = k * 256 + tid;
        int t = idx >> 4, gg = idx & 15;
        int4 v = *(const int4*)&sY[t * 136 + gg * 8];
        *(int4*)&yB[(mbase + t) * D_INNER + h * HEADDIM + gg * 8] = v;
    }
}

// ---------------- K5: y *= silu(z); RMSNorm * norm_w -> bf16 (in place over yB) ----------------
__global__ __launch_bounds__(256) void k5_norm(
    const _Float16* __restrict__ yB, const _Float16* __restrict__ zh,
    const float* __restrict__ nw, ushort* __restrict__ ybB)
{
    const int m = blockIdx.x;
    const int tid = threadIdx.x;
    const size_t off = (size_t)m * D_INNER + tid * 4;
    f16x4 yv = *(const f16x4*)&yB[off];
    f16x4 zv = *(const f16x4*)&zh[off];
    float4 gv;
    {
        float z0 = (float)zv[0], z1 = (float)zv[1], z2 = (float)zv[2], z3 = (float)zv[3];
        gv.x = (float)yv[0] * (z0 / (1.f + expf(-z0)));
        gv.y = (float)yv[1] * (z1 / (1.f + expf(-z1)));
        gv.z = (float)yv[2] * (z2 / (1.f + expf(-z2)));
        gv.w = (float)yv[3] * (z3 / (1.f + expf(-z3)));
    }
    float ss = gv.x*gv.x + gv.y*gv.y + gv.z*gv.z + gv.w*gv.w;
    #pragma unroll
    for (int mask = 1; mask <= 32; mask <<= 1) ss += __shfl_xor(ss, mask);
    __shared__ float red[4];
    if ((tid & 63) == 0) red[tid >> 6] = ss;
    __syncthreads();
    float tot = red[0] + red[1] + red[2] + red[3];
    float scale = rsqrtf(tot * (1.f / 1024.f) + 1e-5f);
    float4 w4 = *(const float4*)(nw + tid * 4);
    ushort4 ob;
    ob.x = f2bf(gv.x * scale * w4.x);
    ob.y = f2bf(gv.y * scale * w4.y);
    ob.z = f2bf(gv.z * scale * w4.z);
    ob.w = f2bf(gv.w * scale * w4.w);
    *(ushort4*)(ybB + off) = ob;
}

// ---------------- K6: out_proj GEMM bf16 MFMA + residual, BK=32 global_load_lds ----------------
__global__ __launch_bounds__(256) void k6_mfma(
    const ushort* __restrict__ A, const ushort* __restrict__ B,
    const float* __restrict__ x, float* __restrict__ out)
{
    __shared__ ushort sA[128 * 32];
    __shared__ ushort sB[128 * 32];
    const int tid = threadIdx.x;
    const int lane = tid & 63;
    const int wv = tid >> 6;
    const int wm = (wv & 1) * 64, wn = (wv >> 1) * 64;
    const int m0 = blockIdx.x * 128;
    const int n0 = blockIdx.y * 128;

    f32x4 acc[4][4];
    #pragma unroll
    for (int i = 0; i < 4; ++i)
        #pragma unroll
        for (int j = 0; j < 4; ++j) acc[i][j] = (f32x4){0.f, 0.f, 0.f, 0.f};

    const int r0 = tid >> 2, c0 = tid & 3, k80 = c0 ^ ((r0 >> 1) & 3);
    const int s1_ = tid + 256;
    const int r1 = s1_ >> 2, c1 = s1_ & 3, k81 = c1 ^ ((r1 >> 1) & 3);
    const int quad = lane >> 4, col = lane & 15;
    ushort* lA0 = sA + (size_t)(wv * 64) * 8;
    ushort* lA1 = sA + (size_t)(256 + wv * 64) * 8;
    ushort* lB0 = sB + (size_t)(wv * 64) * 8;
    ushort* lB1 = sB + (size_t)(256 + wv * 64) * 8;

    for (int kb = 0; kb < D_INNER; kb += 32) {
        gload_lds16(A + (size_t)(m0 + r0) * D_INNER + kb + k80 * 8, lA0);
        gload_lds16(A + (size_t)(m0 + r1) * D_INNER + kb + k81 * 8, lA1);
        gload_lds16(B + (size_t)(n0 + r0) * D_INNER + kb + k80 * 8, lB0);
        gload_lds16(B + (size_t)(n0 + r1) * D_INNER + kb + k81 * 8, lB1);
        __syncthreads();
        bf16x8 af[4], bf_[4];
        #pragma unroll
        for (int mi = 0; mi < 4; ++mi) {
            int m = wm + mi * 16 + col;
            int ch = quad ^ ((m >> 1) & 3);
            af[mi] = *(const bf16x8*)&sA[m * 32 + ch * 8];
        }
        #pragma unroll
        for (int ni = 0; ni < 4; ++ni) {
            int n = wn + ni * 16 + col;
            int ch = quad ^ ((n >> 1) & 3);
            bf_[ni] = *(const bf16x8*)&sB[n * 32 + ch * 8];
        }
        #pragma unroll
        for (int mi = 0; mi < 4; ++mi)
            #pragma unroll
            for (int ni = 0; ni < 4; ++ni)
                acc[mi][ni] = __builtin_amdgcn_mfma_f32_16x16x32_bf16(af[mi], bf_[ni], acc[mi][ni], 0, 0, 0);
        __syncthreads();
    }

    #pragma unroll
    for (int mi = 0; mi < 4; ++mi) {
        #pragma unroll
        for (int ni = 0; ni < 4; ++ni) {
            int mm = n0 + wn + ni * 16 + col;
            int b = mm >> 12, l = mm & 4095;
            #pragma unroll
            for (int reg = 0; reg < 4; ++reg) {
                int d = m0 + wm + mi * 16 + quad * 4 + reg;
                size_t o = ((size_t)(b * DIMC + d) << 12) + l;
                out[o] = acc[mi][ni][reg] + x[o];
            }
        }
    }
}

extern "C" void kernel_launch(void* const* d_in, const int* in_sizes, int n_in,
                              void* d_out, int out_size, void* d_ws, size_t ws_size,
                              hipStream_t stream) {
    const float* x          = (const float*)d_in[0];
    const float* in_proj_w  = (const float*)d_in[1];
    const float* conv_w     = (const float*)d_in[2];
    const float* conv_b     = (const float*)d_in[3];
    const float* dt_bias    = (const float*)d_in[4];
    const float* A_log      = (const float*)d_in[5];
    const float* D_param    = (const float*)d_in[6];
    const float* norm_w     = (const float*)d_in[7];
    const float* out_proj_w = (const float*)d_in[8];
    float* out = (float*)d_out;

    float* ws = (float*)d_ws;
    float* zbuf = ws;                                      // region A: 16,777,216 f32
    _Float16* zh = (_Float16*)zbuf;                        // z stored f16
    float* regB = zbuf + (size_t)16777216;
    _Float16* xbcPre = (_Float16*)regB;                    // 16384x1280 f16
    _Float16* yB     = (_Float16*)regB;                    // 16384x1024 f16 (after k3)
    float* dtb  = regB + (size_t)10485760;
    float* dtp  = dtb + 131072;
    float* ldA  = dtp + 131072;
    float* Pbuf = ldA + 131072;                            // 2048
    float* regD = Pbuf + 2048;
    ushort* xT_k1 = (ushort*)regD;                         // 16384x512 bf16
    ushort* Wb    = xT_k1 + (size_t)BLTOT * DIMC;          // 2432x512 bf16
    _Float16* ST  = (_Float16*)regD;                       // 32x64x128x128 f16 (after k1)
    float* regE = regD + (size_t)16777216;
    _Float16* xsT   = (_Float16*)regE;                     // 4x1024x4096 f16
    _Float16* BT    = xsT + (size_t)BSZ * D_INNER * LSEQ;  // 4x128x4096 f16
    _Float16* bcNat = BT + (size_t)BSZ * D_STATE * LSEQ;   // 16384x256 f16
    ushort* woutB   = (ushort*)(bcNat + (size_t)BLTOT * 256);  // 512x1024 bf16 (independent slot)

    k0_prep<<<dim3(9920), dim3(256), 0, stream>>>(x, xT_k1, in_proj_w, Wb, out_proj_w, woutB);
    k1_mfma<<<dim3(128, 19), dim3(256), 0, stream>>>(xT_k1, Wb, zh, xbcPre, dtb);
    k2_dt<<<dim3(512), dim3(256), 0, stream>>>(dtb, dt_bias, A_log, dtp, ldA);
    k3_conv<<<dim3(20480), dim3(256), 0, stream>>>(xbcPre, conv_w, conv_b, xsT, bcNat, BT);
    k4aA<<<dim3(2048), dim3(256), 0, stream>>>(xsT, BT, dtp, ldA, ST, Pbuf);
    k4bB<<<dim3(512), dim3(256), 0, stream>>>(ST, Pbuf);
    k4cC<<<dim3(2048), dim3(256), 0, stream>>>(bcNat, xsT, ST, dtp, ldA, D_param, yB);
    k5_norm<<<dim3(BLTOT), dim3(256), 0, stream>>>(yB, zh, norm_w, (ushort*)yB);
    k6_mfma<<<dim3(4, 128), dim3(256), 0, stream>>>(woutB, (ushort*)yB, x, out);
}

// Round 12
// 359.356 us; speedup vs baseline: 1.5588x; 1.0872x over previous
//
#include <hip/hip_runtime.h>
#include <cstdint>
#include <cstddef>

#define DIMC     512
#define D_INNER  1024
#define HEADDIM  128
#define NHEADS   8
#define D_STATE  128
#define CONV_DIM 1280
#define D_IN_PROJ 2312
#define NPAD     2432
#define BSZ      4
#define LSEQ     4096
#define BLTOT    (BSZ*LSEQ)   // 16384
#define QC       64           // SSD chunk length
#define NCH      (LSEQ/QC)    // 64 chunks

typedef short bf16x8 __attribute__((ext_vector_type(8)));
typedef float f32x4  __attribute__((ext_vector_type(4)));
typedef _Float16 f16x8 __attribute__((ext_vector_type(8)));
typedef _Float16 f16x4 __attribute__((ext_vector_type(4)));

__device__ inline ushort f2bf(float f) {
    uint32_t u = __float_as_uint(f);
    uint32_t r = (u + 0x7FFFu + ((u >> 16) & 1u)) >> 16;
    return (ushort)r;
}

// async global->LDS, 16B per lane; lds base must be wave-uniform
__device__ __forceinline__ void gload_lds16(const void* g, void* l) {
    __builtin_amdgcn_global_load_lds(
        (const __attribute__((address_space(1))) void*)g,
        (__attribute__((address_space(3))) void*)l,
        16, 0, 0);
}

// ---------------- K0: fused prep. blocks [0,8192): x transpose->bf16; [8192,9408): Wb; [9408,9920): wout ----------------
__global__ __launch_bounds__(256) void k0_prep(
    const float* __restrict__ x, ushort* __restrict__ xT,
    const float* __restrict__ Win, ushort* __restrict__ Wb,
    const float* __restrict__ Wout, ushort* __restrict__ WoutB)
{
    const int bx = blockIdx.x;
    if (bx < 8192) {
        __shared__ float t[32][33];
        const int lt = bx & 127, dt = (bx >> 7) & 15, b = bx >> 11;
        const int r = threadIdx.x >> 5, c = threadIdx.x & 31;
        #pragma unroll
        for (int i = 0; i < 4; ++i) {
            int d = dt * 32 + r + i * 8;
            t[r + i * 8][c] = x[((size_t)(b * DIMC + d) << 12) + lt * 32 + c];
        }
        __syncthreads();
        #pragma unroll
        for (int i = 0; i < 4; ++i) {
            int l = lt * 32 + r + i * 8;
            xT[((size_t)(b * LSEQ + l)) * DIMC + dt * 32 + c] = f2bf(t[c][r + i * 8]);
        }
    } else if (bx < 9408) {
        int i4 = ((bx - 8192) * 256 + threadIdx.x) * 4;   // NPAD*512
        int e = i4 >> 9;
        ushort4 o;
        if (e < D_IN_PROJ) {
            float4 v = *(const float4*)(Win + (size_t)e * DIMC + (i4 & 511));
            o.x = f2bf(v.x); o.y = f2bf(v.y); o.z = f2bf(v.z); o.w = f2bf(v.w);
        } else { o.x = o.y = o.z = o.w = 0; }
        *(ushort4*)(Wb + i4) = o;
    } else {
        int i4 = ((bx - 9408) * 256 + threadIdx.x) * 4;   // 512*1024
        float4 v = *(const float4*)(Wout + i4);
        ushort4 o;
        o.x = f2bf(v.x); o.y = f2bf(v.y); o.z = f2bf(v.z); o.w = f2bf(v.w);
        *(ushort4*)(WoutB + i4) = o;
    }
}

// ---------------- K1: in_proj GEMM, bf16 MFMA, BK=32 global_load_lds (R7-exact structure) ----------------
__global__ __launch_bounds__(256) void k1_mfma(
    const ushort* __restrict__ A, const ushort* __restrict__ B,
    _Float16* __restrict__ zh, _Float16* __restrict__ xbcPre, float* __restrict__ dtb)
{
    __shared__ ushort sA[128 * 32];
    __shared__ ushort sB[128 * 32];
    const int tid = threadIdx.x;
    const int lane = tid & 63;
    const int wv = tid >> 6;
    const int wm = (wv & 1) * 64, wn = (wv >> 1) * 64;
    const int m0 = blockIdx.x * 128;
    const int n0 = blockIdx.y * 128;

    f32x4 acc[4][4];
    #pragma unroll
    for (int i = 0; i < 4; ++i)
        #pragma unroll
        for (int j = 0; j < 4; ++j) acc[i][j] = (f32x4){0.f, 0.f, 0.f, 0.f};

    const int r0 = tid >> 2, c0 = tid & 3, k80 = c0 ^ ((r0 >> 1) & 3);
    const int s1_ = tid + 256;
    const int r1 = s1_ >> 2, c1 = s1_ & 3, k81 = c1 ^ ((r1 >> 1) & 3);
    const int quad = lane >> 4, col = lane & 15;
    ushort* lA0 = sA + (size_t)(wv * 64) * 8;
    ushort* lA1 = sA + (size_t)(256 + wv * 64) * 8;
    ushort* lB0 = sB + (size_t)(wv * 64) * 8;
    ushort* lB1 = sB + (size_t)(256 + wv * 64) * 8;

    for (int kb = 0; kb < DIMC; kb += 32) {
        gload_lds16(A + (size_t)(m0 + r0) * DIMC + kb + k80 * 8, lA0);
        gload_lds16(A + (size_t)(m0 + r1) * DIMC + kb + k81 * 8, lA1);
        gload_lds16(B + (size_t)(n0 + r0) * DIMC + kb + k80 * 8, lB0);
        gload_lds16(B + (size_t)(n0 + r1) * DIMC + kb + k81 * 8, lB1);
        __syncthreads();
        bf16x8 af[4], bf_[4];
        #pragma unroll
        for (int mi = 0; mi < 4; ++mi) {
            int m = wm + mi * 16 + col;
            int ch = quad ^ ((m >> 1) & 3);
            af[mi] = *(const bf16x8*)&sA[m * 32 + ch * 8];
        }
        #pragma unroll
        for (int ni = 0; ni < 4; ++ni) {
            int n = wn + ni * 16 + col;
            int ch = quad ^ ((n >> 1) & 3);
            bf_[ni] = *(const bf16x8*)&sB[n * 32 + ch * 8];
        }
        #pragma unroll
        for (int mi = 0; mi < 4; ++mi)
            #pragma unroll
            for (int ni = 0; ni < 4; ++ni)
                acc[mi][ni] = __builtin_amdgcn_mfma_f32_16x16x32_bf16(af[mi], bf_[ni], acc[mi][ni], 0, 0, 0);
        __syncthreads();
    }

    #pragma unroll
    for (int mi = 0; mi < 4; ++mi) {
        #pragma unroll
        for (int ni = 0; ni < 4; ++ni) {
            int e = n0 + wn + ni * 16 + col;
            #pragma unroll
            for (int reg = 0; reg < 4; ++reg) {
                int m = m0 + wm + mi * 16 + quad * 4 + reg;
                float v = acc[mi][ni][reg];
                if (e < D_INNER)                  zh[(size_t)m * D_INNER + e] = (_Float16)v;
                else if (e < D_INNER + CONV_DIM)  xbcPre[(size_t)m * CONV_DIM + (e - D_INNER)] = (_Float16)v;
                else if (e < D_IN_PROJ)           dtb[(size_t)m * NHEADS + (e - (D_INNER + CONV_DIM))] = v;
            }
        }
    }
}

// ---------------- K2: softplus(dt + bias) -> dtp; ldA = dtp * (-exp(A_log)) ----------------
__global__ __launch_bounds__(256) void k2_dt(
    const float* __restrict__ dtb, const float* __restrict__ dt_bias,
    const float* __restrict__ A_log, float* __restrict__ dtp, float* __restrict__ ldA)
{
    int idx = blockIdx.x * 256 + threadIdx.x;
    if (idx >= BLTOT * NHEADS) return;
    int h = idx & 7;
    float v = dtb[idx] + dt_bias[h];
    float sp = (v > 20.f) ? v : log1pf(expf(v));
    dtp[idx] = sp;
    ldA[idx] = sp * (-expf(A_log[h]));
}

// ---------------- K3: fused conv+silu, vectorized weight loads ----------------
// blocks [0,16384): x-channels -> xsT; [16384,20480): B/C channels -> bcNat + BT
__global__ __launch_bounds__(256) void k3_conv(
    const _Float16* __restrict__ xbcPre, const float* __restrict__ cw,
    const float* __restrict__ cb, _Float16* __restrict__ xsT,
    _Float16* __restrict__ bcNat, _Float16* __restrict__ BT)
{
    __shared__ _Float16 tT[32][36];
    const int tid = threadIdx.x;
    const int tq = tid >> 3, cg = tid & 7;
    const float4* cw4 = (const float4*)cw;   // cw[channel][4] rows are float4
    if (blockIdx.x < 16384) {
        const int bx = blockIdx.x;
        const int ct = bx & 31, tt = (bx >> 5) & 127, b = bx >> 12;
        const int t0 = tt * 32, c0 = ct * 32;
        const int t = t0 + tq;
        const int c = c0 + cg * 4;
        const int m = b * LSEQ + t;

        float4 b4 = *(const float4*)&cb[c];
        float4 w0 = cw4[c], w1 = cw4[c + 1], w2 = cw4[c + 2], w3 = cw4[c + 3];
        float acc[4] = {b4.x, b4.y, b4.z, b4.w};
        {   // tap j=0 (weight idx 3)
            f16x4 xv = *(const f16x4*)&xbcPre[(size_t)m * CONV_DIM + c];
            acc[0] = fmaf((float)xv[0], w0.w, acc[0]);
            acc[1] = fmaf((float)xv[1], w1.w, acc[1]);
            acc[2] = fmaf((float)xv[2], w2.w, acc[2]);
            acc[3] = fmaf((float)xv[3], w3.w, acc[3]);
        }
        if (t >= 1) {   // tap j=1 (weight idx 2)
            f16x4 xv = *(const f16x4*)&xbcPre[(size_t)(m - 1) * CONV_DIM + c];
            acc[0] = fmaf((float)xv[0], w0.z, acc[0]);
            acc[1] = fmaf((float)xv[1], w1.z, acc[1]);
            acc[2] = fmaf((float)xv[2], w2.z, acc[2]);
            acc[3] = fmaf((float)xv[3], w3.z, acc[3]);
        }
        if (t >= 2) {   // tap j=2 (weight idx 1)
            f16x4 xv = *(const f16x4*)&xbcPre[(size_t)(m - 2) * CONV_DIM + c];
            acc[0] = fmaf((float)xv[0], w0.y, acc[0]);
            acc[1] = fmaf((float)xv[1], w1.y, acc[1]);
            acc[2] = fmaf((float)xv[2], w2.y, acc[2]);
            acc[3] = fmaf((float)xv[3], w3.y, acc[3]);
        }
        if (t >= 3) {   // tap j=3 (weight idx 0)
            f16x4 xv = *(const f16x4*)&xbcPre[(size_t)(m - 3) * CONV_DIM + c];
            acc[0] = fmaf((float)xv[0], w0.x, acc[0]);
            acc[1] = fmaf((float)xv[1], w1.x, acc[1]);
            acc[2] = fmaf((float)xv[2], w2.x, acc[2]);
            acc[3] = fmaf((float)xv[3], w3.x, acc[3]);
        }
        #pragma unroll
        for (int i = 0; i < 4; ++i) {
            float s = acc[i] / (1.f + expf(-acc[i]));
            tT[cg * 4 + i][tq] = (_Float16)s;
        }
        __syncthreads();
        const int r = tid >> 3, g = tid & 7;
        f16x4 o = *(const f16x4*)&tT[r][g * 4];
        *(f16x4*)&xsT[((size_t)b * D_INNER + c0 + r) * LSEQ + t0 + g * 4] = o;
    } else {
        const int bx = blockIdx.x - 16384;
        const int ct = bx & 7, tt = (bx >> 3) & 127, b = bx >> 10;
        const int t0 = tt * 32, c0 = ct * 32;
        const int t = t0 + tq;
        const int ca = 1024 + c0 + cg * 4;
        const int m = b * LSEQ + t;

        float4 b4 = *(const float4*)&cb[ca];
        float4 w0 = cw4[ca], w1 = cw4[ca + 1], w2 = cw4[ca + 2], w3 = cw4[ca + 3];
        float acc[4] = {b4.x, b4.y, b4.z, b4.w};
        {
            f16x4 xv = *(const f16x4*)&xbcPre[(size_t)m * CONV_DIM + ca];
            acc[0] = fmaf((float)xv[0], w0.w, acc[0]);
            acc[1] = fmaf((float)xv[1], w1.w, acc[1]);
            acc[2] = fmaf((float)xv[2], w2.w, acc[2]);
            acc[3] = fmaf((float)xv[3], w3.w, acc[3]);
        }
        if (t >= 1) {
            f16x4 xv = *(const f16x4*)&xbcPre[(size_t)(m - 1) * CONV_DIM + ca];
            acc[0] = fmaf((float)xv[0], w0.z, acc[0]);
            acc[1] = fmaf((float)xv[1], w1.z, acc[1]);
            acc[2] = fmaf((float)xv[2], w2.z, acc[2]);
            acc[3] = fmaf((float)xv[3], w3.z, acc[3]);
        }
        if (t >= 2) {
            f16x4 xv = *(const f16x4*)&xbcPre[(size_t)(m - 2) * CONV_DIM + ca];
            acc[0] = fmaf((float)xv[0], w0.y, acc[0]);
            acc[1] = fmaf((float)xv[1], w1.y, acc[1]);
            acc[2] = fmaf((float)xv[2], w2.y, acc[2]);
            acc[3] = fmaf((float)xv[3], w3.y, acc[3]);
        }
        if (t >= 3) {
            f16x4 xv = *(const f16x4*)&xbcPre[(size_t)(m - 3) * CONV_DIM + ca];
            acc[0] = fmaf((float)xv[0], w0.x, acc[0]);
            acc[1] = fmaf((float)xv[1], w1.x, acc[1]);
            acc[2] = fmaf((float)xv[2], w2.x, acc[2]);
            acc[3] = fmaf((float)xv[3], w3.x, acc[3]);
        }
        f16x4 nat;
        #pragma unroll
        for (int i = 0; i < 4; ++i) {
            float s = acc[i] / (1.f + expf(-acc[i]));
            nat[i] = (_Float16)s;
            tT[cg * 4 + i][tq] = nat[i];
        }
        *(f16x4*)&bcNat[(size_t)m * 256 + c0 + cg * 4] = nat;
        if (ct < 4) {
            __syncthreads();
            const int r = tid >> 3, g = tid & 7;
            f16x4 o = *(const f16x4*)&tT[r][g * 4];
            *(f16x4*)&BT[((size_t)b * D_STATE + c0 + r) * LSEQ + t0 + g * 4] = o;
        }
    }
}

// ---------------- K4aA: per-chunk local state GEMM ----------------
__global__ __launch_bounds__(256) void k4aA(
    const _Float16* __restrict__ xsT, const _Float16* __restrict__ BT,
    const float* __restrict__ dtp, const float* __restrict__ ldA,
    _Float16* __restrict__ ST, float* __restrict__ Pbuf)
{
    __shared__ char smem[128 * 72 * 2 * 2 + 512];
    _Float16* sXTs = (_Float16*)smem;
    _Float16* sBT  = sXTs + 128 * 72;
    float* sW = (float*)(sBT + 128 * 72);
    _Float16* sOut = sXTs;

    const int tid = threadIdx.x;
    const int lane = tid & 63;
    const int wv = tid >> 6;
    const int quad = lane >> 4, l15 = lane & 15;
    const int c = blockIdx.x & 63;
    const int h = (blockIdx.x >> 6) & 7;
    const int b = blockIdx.x >> 9;
    const int bh = b * NHEADS + h;
    const size_t mbase = (size_t)b * LSEQ + c * QC;

    if (tid < 64) {
        size_t gi = (mbase + tid) * NHEADS + h;
        float ld = ldA[gi];
        float dtv = dtp[gi];
        float cum = ld;
        #pragma unroll
        for (int off = 1; off < 64; off <<= 1) {
            float v = __shfl_up(cum, off);
            if (tid >= off) cum += v;
        }
        float cum63 = __shfl(cum, 63);
        sW[tid] = expf(cum63 - cum) * dtv;
        if (tid == 63) Pbuf[bh * NCH + c] = expf(cum63);
    }
    __syncthreads();

    #pragma unroll
    for (int k = 0; k < 4; ++k) {
        int idx = k * 256 + tid;
        int row = idx >> 3, g = idx & 7;
        int t0 = g * 8;
        f16x8 hv = *(const f16x8*)&xsT[((size_t)b * D_INNER + h * HEADDIM + row) * LSEQ + c * QC + t0];
        f16x8 sv;
        #pragma unroll
        for (int j = 0; j < 8; ++j) sv[j] = (_Float16)((float)hv[j] * sW[t0 + j]);
        *(f16x8*)&sXTs[row * 72 + t0] = sv;
        int4 bv = *(const int4*)&BT[((size_t)b * D_STATE + row) * LSEQ + c * QC + t0];
        *(int4*)&sBT[row * 72 + t0] = bv;
    }
    __syncthreads();

    f32x4 acc[2][8];
    #pragma unroll
    for (int i = 0; i < 2; ++i)
        #pragma unroll
        for (int j = 0; j < 8; ++j) acc[i][j] = (f32x4){0.f, 0.f, 0.f, 0.f};

    #pragma unroll
    for (int kk = 0; kk < 2; ++kk) {
        f16x8 af[2];
        #pragma unroll
        for (int mi = 0; mi < 2; ++mi)
            af[mi] = *(const f16x8*)&sXTs[(wv * 32 + mi * 16 + l15) * 72 + kk * 32 + quad * 8];
        #pragma unroll
        for (int ni = 0; ni < 8; ++ni) {
            f16x8 bf_ = *(const f16x8*)&sBT[(ni * 16 + l15) * 72 + kk * 32 + quad * 8];
            #pragma unroll
            for (int mi = 0; mi < 2; ++mi)
                acc[mi][ni] = __builtin_amdgcn_mfma_f32_16x16x32_f16(af[mi], bf_, acc[mi][ni], 0, 0, 0);
        }
    }
    __syncthreads();
    #pragma unroll
    for (int mi = 0; mi < 2; ++mi)
        #pragma unroll
        for (int ni = 0; ni < 8; ++ni)
            #pragma unroll
            for (int reg = 0; reg < 4; ++reg) {
                int p = wv * 32 + mi * 16 + quad * 4 + reg;
                int n = ni * 16 + l15;
                sOut[p * 136 + n] = (_Float16)acc[mi][ni][reg];
            }
    __syncthreads();
    _Float16* stg = ST + ((size_t)bh * NCH + c) * (HEADDIM * D_STATE);
    #pragma unroll
    for (int k = 0; k < 8; ++k) {
        int idx = k * 256 + tid;
        int row = idx >> 4, g = idx & 15;
        int4 v = *(const int4*)&sOut[row * 136 + g * 8];
        *(int4*)&stg[row * 128 + g * 8] = v;
    }
}

// ---------------- K4bB: 64-chunk state prefix (in place) ----------------
__global__ __launch_bounds__(256) void k4bB(_Float16* __restrict__ ST, const float* __restrict__ Pbuf)
{
    __shared__ float sp_[NCH];
    const int bh = blockIdx.x >> 4;
    const int seg = blockIdx.x & 15;
    const int tid = threadIdx.x;
    if (tid < NCH) sp_[tid] = Pbuf[bh * NCH + tid];
    __syncthreads();
    const int e = seg * 1024 + tid * 4;
    float r0 = 0.f, r1 = 0.f, r2 = 0.f, r3 = 0.f;
    for (int c = 0; c < NCH; ++c) {
        _Float16* ptr = ST + ((size_t)bh * NCH + c) * (HEADDIM * D_STATE) + e;
        f16x4 v = *(const f16x4*)ptr;
        float f0 = (float)v[0], f1 = (float)v[1], f2 = (float)v[2], f3 = (float)v[3];
        f16x4 o; o[0] = (_Float16)r0; o[1] = (_Float16)r1; o[2] = (_Float16)r2; o[3] = (_Float16)r3;
        *(f16x4*)ptr = o;
        float P = sp_[c];
        r0 = fmaf(r0, P, f0); r1 = fmaf(r1, P, f1);
        r2 = fmaf(r2, P, f2); r3 = fmaf(r3, P, f3);
    }
}

// ---------------- K4cC: per-chunk y via SSD GEMMs ----------------
__global__ __launch_bounds__(256) void k4cC(
    const _Float16* __restrict__ bcNat, const _Float16* __restrict__ xsT,
    const _Float16* __restrict__ sinit, const float* __restrict__ dtp,
    const float* __restrict__ ldA, const float* __restrict__ Dp,
    _Float16* __restrict__ yB)
{
    __shared__ char smem[(64*136 + 64*136 + 128*72 + 4*16*72) * 2 + 640];
    _Float16* sC  = (_Float16*)smem;
    _Float16* sB  = sC + 64 * 136;
    _Float16* sXT = sB + 64 * 136;
    _Float16* sM  = sXT + 128 * 72;
    float* scum = (float*)(sM + 4 * 16 * 72);
    float* sdt  = scum + 64;
    _Float16* sIni = sB;
    _Float16* sY  = sC;

    const int tid = threadIdx.x;
    const int lane = tid & 63;
    const int wv = tid >> 6;
    const int quad = lane >> 4, l15 = lane & 15;
    const int c = blockIdx.x & 63;
    const int h = (blockIdx.x >> 6) & 7;
    const int b = blockIdx.x >> 9;
    const int bh = b * NHEADS + h;
    const size_t mbase = (size_t)b * LSEQ + c * QC;
    const float Dh = Dp[h];

    if (tid < 64) {
        size_t gi = (mbase + tid) * NHEADS + h;
        float ld = ldA[gi];
        float dtv = dtp[gi];
        float cum = ld;
        #pragma unroll
        for (int off = 1; off < 64; off <<= 1) {
            float v = __shfl_up(cum, off);
            if (tid >= off) cum += v;
        }
        scum[tid] = cum;
        sdt[tid] = dtv;
    }
    #pragma unroll
    for (int k = 0; k < 4; ++k) {
        int idx = k * 256 + tid;
        int t = idx >> 4, g = idx & 15;
        const _Float16* row = bcNat + (mbase + t) * 256;
        *(int4*)&sB[t * 136 + g * 8] = *(const int4*)&row[g * 8];
        *(int4*)&sC[t * 136 + g * 8] = *(const int4*)&row[128 + g * 8];
        int idx2 = k * 256 + tid;
        int p = idx2 >> 3, g2 = idx2 & 7;
        *(int4*)&sXT[p * 72 + g2 * 8] =
            *(const int4*)&xsT[((size_t)b * D_INNER + h * HEADDIM + p) * LSEQ + c * QC + g2 * 8];
    }
    __syncthreads();

    // G = C @ B^T
    f32x4 g[4];
    #pragma unroll
    for (int j = 0; j < 4; ++j) g[j] = (f32x4){0.f, 0.f, 0.f, 0.f};
    #pragma unroll
    for (int kk = 0; kk < 4; ++kk) {
        f16x8 af = *(const f16x8*)&sC[(wv * 16 + l15) * 136 + kk * 32 + quad * 8];
        #pragma unroll
        for (int tt = 0; tt < 4; ++tt) {
            f16x8 bf_ = *(const f16x8*)&sB[(tt * 16 + l15) * 136 + kk * 32 + quad * 8];
            g[tt] = __builtin_amdgcn_mfma_f32_16x16x32_f16(af, bf_, g[tt], 0, 0, 0);
        }
    }
    _Float16* sMw = sM + wv * 16 * 72;
    #pragma unroll
    for (int tt = 0; tt < 4; ++tt) {
        int tau = tt * 16 + l15;
        #pragma unroll
        for (int reg = 0; reg < 4; ++reg) {
            int trow = quad * 4 + reg;
            int tglob = wv * 16 + trow;
            float mval;
            if (tau > tglob) mval = 0.f;
            else if (tau == tglob) mval = g[tt][reg] * sdt[tau] + Dh;
            else mval = g[tt][reg] * expf(scum[tglob] - scum[tau]) * sdt[tau];
            sMw[trow * 72 + tau] = (_Float16)mval;
        }
    }
    asm volatile("s_waitcnt lgkmcnt(0)" ::: "memory");

    // Y1 = M @ X^T
    f32x4 y[8];
    #pragma unroll
    for (int j = 0; j < 8; ++j) y[j] = (f32x4){0.f, 0.f, 0.f, 0.f};
    #pragma unroll
    for (int kk = 0; kk < 2; ++kk) {
        f16x8 af = *(const f16x8*)&sMw[l15 * 72 + kk * 32 + quad * 8];
        #pragma unroll
        for (int pi = 0; pi < 8; ++pi) {
            f16x8 bf_ = *(const f16x8*)&sXT[(pi * 16 + l15) * 72 + kk * 32 + quad * 8];
            y[pi] = __builtin_amdgcn_mfma_f32_16x16x32_f16(af, bf_, y[pi], 0, 0, 0);
        }
    }
    __syncthreads();
    {
        const _Float16* sg = sinit + ((size_t)bh * NCH + c) * (HEADDIM * D_STATE);
        #pragma unroll
        for (int k = 0; k < 8; ++k) {
            int idx = k * 256 + tid;
            int p = idx >> 4, gg = idx & 15;
            *(int4*)&sIni[p * 136 + gg * 8] = *(const int4*)&sg[p * 128 + gg * 8];
        }
    }
    __syncthreads();
    // Y2 += (e^cum * C) @ s_init^T
    {
        float ea = expf(scum[wv * 16 + l15]);
        #pragma unroll
        for (int kk = 0; kk < 4; ++kk) {
            f16x8 cf = *(const f16x8*)&sC[(wv * 16 + l15) * 136 + kk * 32 + quad * 8];
            f16x8 af;
            #pragma unroll
            for (int j = 0; j < 8; ++j) af[j] = (_Float16)((float)cf[j] * ea);
            #pragma unroll
            for (int pi = 0; pi < 8; ++pi) {
                f16x8 bf_ = *(const f16x8*)&sIni[(pi * 16 + l15) * 136 + kk * 32 + quad * 8];
                y[pi] = __builtin_amdgcn_mfma_f32_16x16x32_f16(af, bf_, y[pi], 0, 0, 0);
            }
        }
    }
    __syncthreads();
    #pragma unroll
    for (int pi = 0; pi < 8; ++pi)
        #pragma unroll
        for (int reg = 0; reg < 4; ++reg) {
            int trow = wv * 16 + quad * 4 + reg;
            int p = pi * 16 + l15;
            sY[trow * 136 + p] = (_Float16)y[pi][reg];
        }
    __syncthreads();
    #pragma unroll
    for (int k = 0; k < 4; ++k) {
        int idx = k * 256 + tid;
        int t = idx >> 4, gg = idx & 15;
        int4 v = *(const int4*)&sY[t * 136 + gg * 8];
        *(int4*)&yB[(mbase + t) * D_INNER + h * HEADDIM + gg * 8] = v;
    }
}

// ---------------- K5: y *= silu(z); RMSNorm * norm_w -> bf16 (in place over yB) ----------------
__global__ __launch_bounds__(256) void k5_norm(
    const _Float16* __restrict__ yB, const _Float16* __restrict__ zh,
    const float* __restrict__ nw, ushort* __restrict__ ybB)
{
    const int m = blockIdx.x;
    const int tid = threadIdx.x;
    const size_t off = (size_t)m * D_INNER + tid * 4;
    f16x4 yv = *(const f16x4*)&yB[off];
    f16x4 zv = *(const f16x4*)&zh[off];
    float4 gv;
    {
        float z0 = (float)zv[0], z1 = (float)zv[1], z2 = (float)zv[2], z3 = (float)zv[3];
        gv.x = (float)yv[0] * (z0 / (1.f + expf(-z0)));
        gv.y = (float)yv[1] * (z1 / (1.f + expf(-z1)));
        gv.z = (float)yv[2] * (z2 / (1.f + expf(-z2)));
        gv.w = (float)yv[3] * (z3 / (1.f + expf(-z3)));
    }
    float ss = gv.x*gv.x + gv.y*gv.y + gv.z*gv.z + gv.w*gv.w;
    #pragma unroll
    for (int mask = 1; mask <= 32; mask <<= 1) ss += __shfl_xor(ss, mask);
    __shared__ float red[4];
    if ((tid & 63) == 0) red[tid >> 6] = ss;
    __syncthreads();
    float tot = red[0] + red[1] + red[2] + red[3];
    float scale = rsqrtf(tot * (1.f / 1024.f) + 1e-5f);
    float4 w4 = *(const float4*)(nw + tid * 4);
    ushort4 ob;
    ob.x = f2bf(gv.x * scale * w4.x);
    ob.y = f2bf(gv.y * scale * w4.y);
    ob.z = f2bf(gv.z * scale * w4.z);
    ob.w = f2bf(gv.w * scale * w4.w);
    *(ushort4*)(ybB + off) = ob;
}

// ---------------- K6: out_proj GEMM bf16 MFMA + residual, BK=32 global_load_lds ----------------
__global__ __launch_bounds__(256) void k6_mfma(
    const ushort* __restrict__ A, const ushort* __restrict__ B,
    const float* __restrict__ x, float* __restrict__ out)
{
    __shared__ ushort sA[128 * 32];
    __shared__ ushort sB[128 * 32];
    const int tid = threadIdx.x;
    const int lane = tid & 63;
    const int wv = tid >> 6;
    const int wm = (wv & 1) * 64, wn = (wv >> 1) * 64;
    const int m0 = blockIdx.x * 128;
    const int n0 = blockIdx.y * 128;

    f32x4 acc[4][4];
    #pragma unroll
    for (int i = 0; i < 4; ++i)
        #pragma unroll
        for (int j = 0; j < 4; ++j) acc[i][j] = (f32x4){0.f, 0.f, 0.f, 0.f};

    const int r0 = tid >> 2, c0 = tid & 3, k80 = c0 ^ ((r0 >> 1) & 3);
    const int s1_ = tid + 256;
    const int r1 = s1_ >> 2, c1 = s1_ & 3, k81 = c1 ^ ((r1 >> 1) & 3);
    const int quad = lane >> 4, col = lane & 15;
    ushort* lA0 = sA + (size_t)(wv * 64) * 8;
    ushort* lA1 = sA + (size_t)(256 + wv * 64) * 8;
    ushort* lB0 = sB + (size_t)(wv * 64) * 8;
    ushort* lB1 = sB + (size_t)(256 + wv * 64) * 8;

    for (int kb = 0; kb < D_INNER; kb += 32) {
        gload_lds16(A + (size_t)(m0 + r0) * D_INNER + kb + k80 * 8, lA0);
        gload_lds16(A + (size_t)(m0 + r1) * D_INNER + kb + k81 * 8, lA1);
        gload_lds16(B + (size_t)(n0 + r0) * D_INNER + kb + k80 * 8, lB0);
        gload_lds16(B + (size_t)(n0 + r1) * D_INNER + kb + k81 * 8, lB1);
        __syncthreads();
        bf16x8 af[4], bf_[4];
        #pragma unroll
        for (int mi = 0; mi < 4; ++mi) {
            int m = wm + mi * 16 + col;
            int ch = quad ^ ((m >> 1) & 3);
            af[mi] = *(const bf16x8*)&sA[m * 32 + ch * 8];
        }
        #pragma unroll
        for (int ni = 0; ni < 4; ++ni) {
            int n = wn + ni * 16 + col;
            int ch = quad ^ ((n >> 1) & 3);
            bf_[ni] = *(const bf16x8*)&sB[n * 32 + ch * 8];
        }
        #pragma unroll
        for (int mi = 0; mi < 4; ++mi)
            #pragma unroll
            for (int ni = 0; ni < 4; ++ni)
                acc[mi][ni] = __builtin_amdgcn_mfma_f32_16x16x32_bf16(af[mi], bf_[ni], acc[mi][ni], 0, 0, 0);
        __syncthreads();
    }

    #pragma unroll
    for (int mi = 0; mi < 4; ++mi) {
        #pragma unroll
        for (int ni = 0; ni < 4; ++ni) {
            int mm = n0 + wn + ni * 16 + col;
            int b = mm >> 12, l = mm & 4095;
            #pragma unroll
            for (int reg = 0; reg < 4; ++reg) {
                int d = m0 + wm + mi * 16 + quad * 4 + reg;
                size_t o = ((size_t)(b * DIMC + d) << 12) + l;
                out[o] = acc[mi][ni][reg] + x[o];
            }
        }
    }
}

extern "C" void kernel_launch(void* const* d_in, const int* in_sizes, int n_in,
                              void* d_out, int out_size, void* d_ws, size_t ws_size,
                              hipStream_t stream) {
    const float* x          = (const float*)d_in[0];
    const float* in_proj_w  = (const float*)d_in[1];
    const float* conv_w     = (const float*)d_in[2];
    const float* conv_b     = (const float*)d_in[3];
    const float* dt_bias    = (const float*)d_in[4];
    const float* A_log      = (const float*)d_in[5];
    const float* D_param    = (const float*)d_in[6];
    const float* norm_w     = (const float*)d_in[7];
    const float* out_proj_w = (const float*)d_in[8];
    float* out = (float*)d_out;

    float* ws = (float*)d_ws;
    float* zbuf = ws;                                      // region A: 16,777,216 f32
    _Float16* zh = (_Float16*)zbuf;                        // z stored f16
    float* regB = zbuf + (size_t)16777216;
    _Float16* xbcPre = (_Float16*)regB;                    // 16384x1280 f16
    _Float16* yB     = (_Float16*)regB;                    // 16384x1024 f16 (after k3)
    float* dtb  = regB + (size_t)10485760;
    float* dtp  = dtb + 131072;
    float* ldA  = dtp + 131072;
    float* Pbuf = ldA + 131072;                            // 2048
    float* regD = Pbuf + 2048;
    ushort* xT_k1 = (ushort*)regD;                         // 16384x512 bf16
    ushort* Wb    = xT_k1 + (size_t)BLTOT * DIMC;          // 2432x512 bf16
    _Float16* ST  = (_Float16*)regD;                       // 32x64x128x128 f16 (after k1)
    float* regE = regD + (size_t)16777216;
    _Float16* xsT   = (_Float16*)regE;                     // 4x1024x4096 f16
    _Float16* BT    = xsT + (size_t)BSZ * D_INNER * LSEQ;  // 4x128x4096 f16
    _Float16* bcNat = BT + (size_t)BSZ * D_STATE * LSEQ;   // 16384x256 f16
    ushort* woutB   = (ushort*)(bcNat + (size_t)BLTOT * 256);  // 512x1024 bf16 (independent slot)

    k0_prep<<<dim3(9920), dim3(256), 0, stream>>>(x, xT_k1, in_proj_w, Wb, out_proj_w, woutB);
    k1_mfma<<<dim3(128, 19), dim3(256), 0, stream>>>(xT_k1, Wb, zh, xbcPre, dtb);
    k2_dt<<<dim3(512), dim3(256), 0, stream>>>(dtb, dt_bias, A_log, dtp, ldA);
    k3_conv<<<dim3(20480), dim3(256), 0, stream>>>(xbcPre, conv_w, conv_b, xsT, bcNat, BT);
    k4aA<<<dim3(2048), dim3(256), 0, stream>>>(xsT, BT, dtp, ldA, ST, Pbuf);
    k4bB<<<dim3(512), dim3(256), 0, stream>>>(ST, Pbuf);
    k4cC<<<dim3(2048), dim3(256), 0, stream>>>(bcNat, xsT, ST, dtp, ldA, D_param, yB);
    k5_norm<<<dim3(BLTOT), dim3(256), 0, stream>>>(yB, zh, norm_w, (ushort*)yB);
    k6_mfma<<<dim3(4, 128), dim3(256), 0, stream>>>(woutB, (ushort*)yB, x, out);
}